// Round 1
// baseline (995.217 us; speedup 1.0000x reference)
//
#include <hip/hip_runtime.h>
#include <cstdint>
#include <cstddef>

// ---------------------------------------------------------------------------
// GCN forward:  softmax( (A_hat relu(A_hat (X W1 + b1) W2)) Wl + bl )
// A_hat = D_in^{-1/2} A D_out^{-1/2}, applied as: scale rows by inv_sqrt_out
// (folded into GEMM epilogue), CSR-gather-sum by dst, scale by inv_sqrt_in.
// All big GEMMs in bf16 MFMA (fp32 accum); threshold is ~2% relative.
// ---------------------------------------------------------------------------

using bf8   = __attribute__((ext_vector_type(8))) short;   // 8 bf16 (4 VGPR)
using s4    = __attribute__((ext_vector_type(4))) short;
using f32x4 = __attribute__((ext_vector_type(4))) float;

static __device__ __forceinline__ unsigned short f2bf(float f) {
    union { float f; uint32_t u; } v; v.f = f;
    uint32_t r = (v.u + 0x7FFFu + ((v.u >> 16) & 1u)) >> 16;   // RNE
    return (unsigned short)r;
}
static __device__ __forceinline__ float bf2f(unsigned short b) {
    union { uint32_t u; float f; } v; v.u = ((uint32_t)b) << 16;
    return v.f;
}

// ---------------- prep kernels ----------------

__global__ void k_zero(float* a, float* b, int* c, int n) {
    int i = blockIdx.x * blockDim.x + threadIdx.x;
    if (i < n) { a[i] = 0.f; b[i] = 0.f; c[i] = 0; }
}

__global__ void k_count(const int* __restrict__ src, const int* __restrict__ dst,
                        float* deg_out, float* deg_in, int E) {
    int e = blockIdx.x * blockDim.x + threadIdx.x;
    if (e < E) {
        atomicAdd(&deg_out[src[e]], 1.f);
        atomicAdd(&deg_in[dst[e]], 1.f);
    }
}

__global__ void k_inv(const float* deg_out, const float* deg_in,
                      float* inv_out, float* inv_in, int n) {
    int i = blockIdx.x * blockDim.x + threadIdx.x;
    if (i < n) {
        inv_out[i] = rsqrtf(fmaxf(deg_out[i], 1.f));
        inv_in[i]  = rsqrtf(fmaxf(deg_in[i], 1.f));
    }
}

// exclusive prefix sum of (int)deg_in over 4096 entries; single block of 1024
__global__ void k_scan(const float* __restrict__ deg_in, int* __restrict__ row_off) {
    __shared__ int part[1024];
    const int t = threadIdx.x;
    int v0 = (int)deg_in[t*4+0], v1 = (int)deg_in[t*4+1],
        v2 = (int)deg_in[t*4+2], v3 = (int)deg_in[t*4+3];
    part[t] = v0 + v1 + v2 + v3;
    __syncthreads();
    for (int off = 1; off < 1024; off <<= 1) {
        int x = (t >= off) ? part[t - off] : 0;
        __syncthreads();
        part[t] += x;
        __syncthreads();
    }
    int run = (t == 0) ? 0 : part[t-1];
    row_off[t*4+0] = run; run += v0;
    row_off[t*4+1] = run; run += v1;
    row_off[t*4+2] = run; run += v2;
    row_off[t*4+3] = run; run += v3;
    if (t == 1023) row_off[4096] = run;   // == E
}

__global__ void k_fill(const int* __restrict__ src, const int* __restrict__ dst,
                       const int* __restrict__ row_off, int* cursor,
                       int* __restrict__ esrc, int E) {
    int e = blockIdx.x * blockDim.x + threadIdx.x;
    if (e < E) {
        int d = dst[e];
        int p = atomicAdd(&cursor[d], 1);
        esrc[row_off[d] + p] = src[e];
    }
}

// fp32 -> bf16 elementwise (n4 = count/4)
__global__ void k_cvt(const float* __restrict__ in, short* __restrict__ out, int n4) {
    int i = blockIdx.x * blockDim.x + threadIdx.x;
    if (i < n4) {
        float4 v = reinterpret_cast<const float4*>(in)[i];
        s4 o;
        o[0] = (short)f2bf(v.x); o[1] = (short)f2bf(v.y);
        o[2] = (short)f2bf(v.z); o[3] = (short)f2bf(v.w);
        reinterpret_cast<s4*>(out)[i] = o;
    }
}

// out[c][r] = (bf16) in[r][c]   -- fp32 [R][C] -> bf16 [C][R].  block (32,8)
__global__ void k_tr(const float* __restrict__ in, short* __restrict__ out, int R, int C) {
    __shared__ float tile[32][33];
    int bc = blockIdx.x * 32, br = blockIdx.y * 32;
    int tx = threadIdx.x, ty = threadIdx.y;
    #pragma unroll
    for (int dy = 0; dy < 32; dy += 8)
        tile[ty + dy][tx] = in[(size_t)(br + ty + dy) * C + bc + tx];
    __syncthreads();
    #pragma unroll
    for (int dy = 0; dy < 32; dy += 8)
        out[(size_t)(bc + ty + dy) * R + br + tx] = (short)f2bf(tile[tx][ty + dy]);
}

// ---------------- bf16 MFMA GEMM ----------------
// C[M][N] = A[M][K] * B[K][N]; A row-major bf16, Bt = B^T row-major bf16 [N][K].
// EPI==1: out = (acc + bias[col]) * rowscale[row]   (GEMM1)
// EPI==2: out = acc * rowscale[row]                 (GEMM2)
// 128x128 tile, BK=32, 256 threads = 4 waves (2x2), each wave 64x64 (4x4 MFMAs).
template<int EPI>
__global__ __launch_bounds__(256)
void gemm_bf16(const short* __restrict__ A, const short* __restrict__ Bt,
               short* __restrict__ C,
               const float* __restrict__ bias, const float* __restrict__ rowscale,
               int M, int N, int K)
{
    __shared__ __align__(16) short lA[128*32];
    __shared__ __align__(16) short lB[128*32];
    const int tid  = threadIdx.x;
    const int tm   = blockIdx.y * 128;
    const int tn   = blockIdx.x * 128;
    const int wid  = tid >> 6, lane = tid & 63;
    const int wr   = (wid >> 1) * 64;      // wave row offset in tile
    const int wc   = (wid & 1) * 64;       // wave col offset in tile
    const int fr   = lane & 15;            // fragment row (A) / col (B)
    const int kg   = (lane >> 4) * 8;      // k-group offset within BK=32

    f32x4 acc[4][4];
    #pragma unroll
    for (int m = 0; m < 4; ++m)
        #pragma unroll
        for (int n = 0; n < 4; ++n)
            acc[m][n] = (f32x4){0.f, 0.f, 0.f, 0.f};

    const int sr0 = tid >> 2;              // staging row 0..63
    const int sc0 = (tid & 3) * 8;         // staging col 0,8,16,24

    for (int k0 = 0; k0 < K; k0 += 32) {
        bf8 a0 = *reinterpret_cast<const bf8*>(A  + (size_t)(tm + sr0)      * K + k0 + sc0);
        bf8 a1 = *reinterpret_cast<const bf8*>(A  + (size_t)(tm + 64 + sr0) * K + k0 + sc0);
        bf8 b0 = *reinterpret_cast<const bf8*>(Bt + (size_t)(tn + sr0)      * K + k0 + sc0);
        bf8 b1 = *reinterpret_cast<const bf8*>(Bt + (size_t)(tn + 64 + sr0) * K + k0 + sc0);
        *reinterpret_cast<bf8*>(lA + sr0 * 32 + sc0)        = a0;
        *reinterpret_cast<bf8*>(lA + (64 + sr0) * 32 + sc0) = a1;
        *reinterpret_cast<bf8*>(lB + sr0 * 32 + sc0)        = b0;
        *reinterpret_cast<bf8*>(lB + (64 + sr0) * 32 + sc0) = b1;
        __syncthreads();

        bf8 af[4], bg[4];
        #pragma unroll
        for (int m = 0; m < 4; ++m)
            af[m] = *reinterpret_cast<const bf8*>(lA + (wr + m*16 + fr) * 32 + kg);
        #pragma unroll
        for (int n = 0; n < 4; ++n)
            bg[n] = *reinterpret_cast<const bf8*>(lB + (wc + n*16 + fr) * 32 + kg);

        #pragma unroll
        for (int m = 0; m < 4; ++m)
            #pragma unroll
            for (int n = 0; n < 4; ++n)
                acc[m][n] = __builtin_amdgcn_mfma_f32_16x16x32_bf16(af[m], bg[n], acc[m][n], 0, 0, 0);
        __syncthreads();
    }

    // epilogue: C/D layout col = lane&15, row = (lane>>4)*4 + reg  [verified m89]
    const int rb = (lane >> 4) * 4;
    #pragma unroll
    for (int m = 0; m < 4; ++m) {
        #pragma unroll
        for (int n = 0; n < 4; ++n) {
            const int col = tn + wc + n*16 + fr;
            const float bcol = (EPI == 1) ? bias[col] : 0.f;
            #pragma unroll
            for (int j = 0; j < 4; ++j) {
                const int row = tm + wr + m*16 + rb + j;
                float v = acc[m][n][j] + bcol;
                v *= rowscale[row];
                C[(size_t)row * N + col] = (short)f2bf(v);
            }
        }
    }
}

// ---------------- CSR aggregation:  Y[i] = inv_in[i] * sum_{e: dst=i} X[src[e]] ----------------
// grid: (F/2048, N); 256 threads, 8 bf16 cols per thread.
template<int RELU>
__global__ __launch_bounds__(256)
void agg_csr(const short* __restrict__ X, short* __restrict__ Y,
             const int* __restrict__ row_off, const int* __restrict__ esrc,
             const float* __restrict__ inv_in, int F)
{
    const int node = blockIdx.y;
    const int c0 = blockIdx.x * 2048 + threadIdx.x * 8;
    float acc[8];
    #pragma unroll
    for (int j = 0; j < 8; ++j) acc[j] = 0.f;

    const int beg = row_off[node], end = row_off[node + 1];
    for (int p = beg; p < end; ++p) {
        const int s = esrc[p];
        bf8 x = *reinterpret_cast<const bf8*>(X + (size_t)s * F + c0);
        #pragma unroll
        for (int j = 0; j < 8; ++j) acc[j] += bf2f((unsigned short)x[j]);
    }
    const float sc = inv_in[node];
    bf8 o;
    #pragma unroll
    for (int j = 0; j < 8; ++j) {
        float v = acc[j] * sc;
        if (RELU) v = fmaxf(v, 0.f);
        o[j] = (short)f2bf(v);
    }
    *reinterpret_cast<bf8*>(Y + (size_t)node * F + c0) = o;
}

// ---------------- head: logits = H[4096] . Wl[4096][16] + bl; softmax ----------------
__global__ __launch_bounds__(256)
void k_head(const short* __restrict__ H, const float* __restrict__ Wl,
            const float* __restrict__ bl, float* __restrict__ out)
{
    const int row = blockIdx.x;
    const int tid = threadIdx.x;
    float acc[16];
    #pragma unroll
    for (int c = 0; c < 16; ++c) acc[c] = 0.f;

    for (int k = tid; k < 4096; k += 256) {
        const float x = bf2f((unsigned short)H[(size_t)row * 4096 + k]);
        const float4* w = reinterpret_cast<const float4*>(Wl + (size_t)k * 16);
        float4 w0 = w[0], w1 = w[1], w2 = w[2], w3 = w[3];
        acc[0]  += x * w0.x; acc[1]  += x * w0.y; acc[2]  += x * w0.z; acc[3]  += x * w0.w;
        acc[4]  += x * w1.x; acc[5]  += x * w1.y; acc[6]  += x * w1.z; acc[7]  += x * w1.w;
        acc[8]  += x * w2.x; acc[9]  += x * w2.y; acc[10] += x * w2.z; acc[11] += x * w2.w;
        acc[12] += x * w3.x; acc[13] += x * w3.y; acc[14] += x * w3.z; acc[15] += x * w3.w;
    }
    // wave reduce (64 lanes)
    #pragma unroll
    for (int c = 0; c < 16; ++c)
        for (int off = 32; off; off >>= 1)
            acc[c] += __shfl_down(acc[c], off, 64);

    __shared__ float sm[16][4];
    const int wid = tid >> 6, lane = tid & 63;
    if (lane == 0) {
        #pragma unroll
        for (int c = 0; c < 16; ++c) sm[c][wid] = acc[c];
    }
    __syncthreads();
    if (tid < 16) {
        float l = sm[tid][0] + sm[tid][1] + sm[tid][2] + sm[tid][3] + bl[tid];
        float mx = l;
        #pragma unroll
        for (int off = 1; off < 16; off <<= 1) mx = fmaxf(mx, __shfl_xor(mx, off, 16));
        float e = expf(l - mx);
        float s = e;
        #pragma unroll
        for (int off = 1; off < 16; off <<= 1) s += __shfl_xor(s, off, 16);
        out[(size_t)row * 16 + tid] = e / s;
    }
}

// ---------------- launch ----------------

extern "C" void kernel_launch(void* const* d_in, const int* in_sizes, int n_in,
                              void* d_out, int out_size, void* d_ws, size_t ws_size,
                              hipStream_t stream)
{
    const float* features = (const float*)d_in[0];
    const float* W1       = (const float*)d_in[1];
    const float* b1       = (const float*)d_in[2];
    const float* W2       = (const float*)d_in[3];
    const float* Wl       = (const float*)d_in[4];
    const float* bl       = (const float*)d_in[5];
    const int*   src      = (const int*)d_in[6];
    const int*   dst      = (const int*)d_in[7];
    float* out = (float*)d_out;

    const int N = 4096, IN = 512, H = 8192;
    const int E = in_sizes[6];

    char* ws = (char*)d_ws;
    size_t o = 0;
    auto alloc = [&](size_t bytes) -> char* {
        char* p = ws + o;
        o = (o + bytes + 255) & ~(size_t)255;
        return p;
    };
    short* W2t   = (short*)alloc((size_t)N * H * 2);     // 64 MB  W2^T bf16 [4096][8192]
    short* x1s   = (short*)alloc((size_t)N * H * 2);     // 64 MB  (XW1+b1)*inv_out bf16; reused below
    short* h1    = (short*)alloc((size_t)N * H * 2);     // 64 MB  conv1 out bf16
    short* featb = (short*)alloc((size_t)N * IN * 2);    // 4 MB
    short* W1t   = (short*)alloc((size_t)H * IN * 2);    // 8 MB   W1^T bf16 [8192][512]
    float* deg_out = (float*)alloc(N * 4);
    float* deg_in  = (float*)alloc(N * 4);
    float* inv_out = (float*)alloc(N * 4);
    float* inv_in  = (float*)alloc(N * 4);
    int*   cursor  = (int*)alloc(N * 4);
    int*   row_off = (int*)alloc((N + 1) * 4);
    int*   esrc    = (int*)alloc((size_t)E * 4);
    // reuse of x1s region after agg1 consumes it:
    short* x2s = x1s;                         // 32 MB  (h1 W2)*inv_out bf16 [4096][4096]
    short* h2  = x1s + (size_t)N * N;         // 32 MB  conv2+relu out bf16 [4096][4096]

    // graph prep
    k_zero <<<(N + 255) / 256, 256, 0, stream>>>(deg_out, deg_in, cursor, N);
    k_count<<<(E + 255) / 256, 256, 0, stream>>>(src, dst, deg_out, deg_in, E);
    k_inv  <<<(N + 255) / 256, 256, 0, stream>>>(deg_out, deg_in, inv_out, inv_in, N);
    k_scan <<<1, 1024, 0, stream>>>(deg_in, row_off);
    k_fill <<<(E + 255) / 256, 256, 0, stream>>>(src, dst, row_off, cursor, esrc, E);

    // operand conversion
    k_cvt<<<(N * IN / 4 + 255) / 256, 256, 0, stream>>>(features, featb, N * IN / 4);
    k_tr <<<dim3(H / 32, IN / 32), dim3(32, 8), 0, stream>>>(W1, W1t, IN, H);
    k_tr <<<dim3(N / 32, H / 32), dim3(32, 8), 0, stream>>>(W2, W2t, H, N);

    // layer 1
    gemm_bf16<1><<<dim3(H / 128, N / 128), 256, 0, stream>>>(featb, W1t, x1s, b1, inv_out, N, H, IN);
    agg_csr<0>  <<<dim3(H / 2048, N), 256, 0, stream>>>(x1s, h1, row_off, esrc, inv_in, H);

    // layer 2
    gemm_bf16<2><<<dim3(N / 128, N / 128), 256, 0, stream>>>(h1, W2t, x2s, nullptr, inv_out, N, N, H);
    agg_csr<1>  <<<dim3(N / 2048, N), 256, 0, stream>>>(x2s, h2, row_off, esrc, inv_in, N);

    // head + softmax
    k_head<<<N, 256, 0, stream>>>(h2, Wl, bl, out);
}

// Round 2
// 739.812 us; speedup vs baseline: 1.3452x; 1.3452x over previous
//
#include <hip/hip_runtime.h>
#include <cstdint>
#include <cstddef>

// ---------------------------------------------------------------------------
// GCN forward:  softmax( (A_hat relu(A_hat (X W1 + b1) W2)) Wl + bl )
// A_hat = D_in^{-1/2} A D_out^{-1/2}.
// conv1 reordered via linearity:  A_hat(X W1 + b1.1^T) = (A_hat X) W1 + (A_hat 1) b1
//   -> aggregate features (F=512) FIRST, then GEMM1 with rowsum*b1 epilogue.
// conv2: project first (8192->4096), then aggregate (smaller side).
// GEMMs: bf16 MFMA 16x16x32, fp32 accum, global_load_lds width-16 staging.
// ---------------------------------------------------------------------------

using bf8   = __attribute__((ext_vector_type(8))) short;   // 8 bf16 (4 VGPR)
using s4    = __attribute__((ext_vector_type(4))) short;
using f32x4 = __attribute__((ext_vector_type(4))) float;

static __device__ __forceinline__ unsigned short f2bf(float f) {
    union { float f; uint32_t u; } v; v.f = f;
    uint32_t r = (v.u + 0x7FFFu + ((v.u >> 16) & 1u)) >> 16;   // RNE
    return (unsigned short)r;
}
static __device__ __forceinline__ float bf2f(unsigned short b) {
    union { uint32_t u; float f; } v; v.u = ((uint32_t)b) << 16;
    return v.f;
}

// async global -> LDS, 16 bytes per lane (m97 pattern; LDS dest must be
// wave-uniform base + lane*16, which our staging layout satisfies: tid*16)
static __device__ __forceinline__ void gload16(const short* g, short* l) {
    __builtin_amdgcn_global_load_lds(
        (const __attribute__((address_space(1))) unsigned int*)g,
        (__attribute__((address_space(3))) unsigned int*)l,
        16, 0, 0);
}

// ---------------- prep kernels ----------------

__global__ void k_zero(float* a, float* b, int* c, int n) {
    int i = blockIdx.x * blockDim.x + threadIdx.x;
    if (i < n) { a[i] = 0.f; b[i] = 0.f; c[i] = 0; }
}

__global__ void k_count(const int* __restrict__ src, const int* __restrict__ dst,
                        float* deg_out, float* deg_in, int E) {
    int e = blockIdx.x * blockDim.x + threadIdx.x;
    if (e < E) {
        atomicAdd(&deg_out[src[e]], 1.f);
        atomicAdd(&deg_in[dst[e]], 1.f);
    }
}

__global__ void k_inv(const float* deg_out, const float* deg_in,
                      float* inv_out, float* inv_in, int n) {
    int i = blockIdx.x * blockDim.x + threadIdx.x;
    if (i < n) {
        inv_out[i] = rsqrtf(fmaxf(deg_out[i], 1.f));
        inv_in[i]  = rsqrtf(fmaxf(deg_in[i], 1.f));
    }
}

// exclusive prefix sum of (int)deg_in over 4096 entries; single block of 1024
__global__ void k_scan(const float* __restrict__ deg_in, int* __restrict__ row_off) {
    __shared__ int part[1024];
    const int t = threadIdx.x;
    int v0 = (int)deg_in[t*4+0], v1 = (int)deg_in[t*4+1],
        v2 = (int)deg_in[t*4+2], v3 = (int)deg_in[t*4+3];
    part[t] = v0 + v1 + v2 + v3;
    __syncthreads();
    for (int off = 1; off < 1024; off <<= 1) {
        int x = (t >= off) ? part[t - off] : 0;
        __syncthreads();
        part[t] += x;
        __syncthreads();
    }
    int run = (t == 0) ? 0 : part[t-1];
    row_off[t*4+0] = run; run += v0;
    row_off[t*4+1] = run; run += v1;
    row_off[t*4+2] = run; run += v2;
    row_off[t*4+3] = run; run += v3;
    if (t == 1023) row_off[4096] = run;   // == E
}

__global__ void k_fill(const int* __restrict__ src, const int* __restrict__ dst,
                       const int* __restrict__ row_off, int* cursor,
                       int* __restrict__ esrc, int E) {
    int e = blockIdx.x * blockDim.x + threadIdx.x;
    if (e < E) {
        int d = dst[e];
        int p = atomicAdd(&cursor[d], 1);
        esrc[row_off[d] + p] = src[e];
    }
}

// rowsum[i] = inv_in[i] * sum_{e: dst=i} inv_out[esrc[e]]   (one wave per node)
__global__ void k_rowsum(const int* __restrict__ row_off, const int* __restrict__ esrc,
                         const float* __restrict__ inv_out, const float* __restrict__ inv_in,
                         float* __restrict__ rowsum) {
    const int node = blockIdx.x, lane = threadIdx.x;
    const int beg = row_off[node], end = row_off[node + 1];
    float s = 0.f;
    for (int p = beg + lane; p < end; p += 64) s += inv_out[esrc[p]];
    #pragma unroll
    for (int off = 32; off; off >>= 1) s += __shfl_down(s, off, 64);
    if (lane == 0) rowsum[node] = s * inv_in[node];
}

// fp32 -> bf16 with per-row scale: out[r][c] = bf16(in[r][c] * sc[r]); n4 = count/4
__global__ void k_cvt_scale(const float* __restrict__ in, const float* __restrict__ sc,
                            short* __restrict__ out, int n4, int f4) {
    int i = blockIdx.x * blockDim.x + threadIdx.x;
    if (i < n4) {
        const float s = sc[i / f4];
        float4 v = reinterpret_cast<const float4*>(in)[i];
        s4 o;
        o[0] = (short)f2bf(v.x * s); o[1] = (short)f2bf(v.y * s);
        o[2] = (short)f2bf(v.z * s); o[3] = (short)f2bf(v.w * s);
        reinterpret_cast<s4*>(out)[i] = o;
    }
}

// out[c][r] = (bf16) in[r][c]   -- fp32 [R][C] -> bf16 [C][R].  block (32,8)
__global__ void k_tr(const float* __restrict__ in, short* __restrict__ out, int R, int C) {
    __shared__ float tile[32][33];
    int bc = blockIdx.x * 32, br = blockIdx.y * 32;
    int tx = threadIdx.x, ty = threadIdx.y;
    #pragma unroll
    for (int dy = 0; dy < 32; dy += 8)
        tile[ty + dy][tx] = in[(size_t)(br + ty + dy) * C + bc + tx];
    __syncthreads();
    #pragma unroll
    for (int dy = 0; dy < 32; dy += 8)
        out[(size_t)(bc + ty + dy) * R + br + tx] = (short)f2bf(tile[tx][ty + dy]);
}

// ---------------- bf16 MFMA GEMM (m97 structure: gload_lds width-16) ----------------
// C[M][N] = A[M][K] * B[K][N]; A row-major bf16, Bt = B^T row-major bf16 [N][K].
// EPI==1: out = acc + rs[row] * bias[col]    (GEMM1: rowsum * b1)
// EPI==2: out = acc * rs[row]                (GEMM2: inv_sqrt_out)
// 128x128 tile, BK=32, 256 threads = 4 waves (2x2), each wave 64x64 (4x4 MFMAs).
template<int EPI>
__global__ __launch_bounds__(256)
void gemm_bf16(const short* __restrict__ A, const short* __restrict__ Bt,
               short* __restrict__ C,
               const float* __restrict__ bias, const float* __restrict__ rs,
               int M, int N, int K)
{
    __shared__ __align__(16) short lA[128*32];
    __shared__ __align__(16) short lB[128*32];
    const int tid  = threadIdx.x;
    const int tm   = blockIdx.y * 128;
    const int tn   = blockIdx.x * 128;
    const int wid  = tid >> 6, lane = tid & 63;
    const int wr   = (wid >> 1) * 64;      // wave row offset in tile
    const int wc   = (wid & 1) * 64;       // wave col offset in tile
    const int fr   = lane & 15;            // fragment row (A) / col (B)
    const int kg   = (lane >> 4) * 8;      // k-group offset within BK=32

    f32x4 acc[4][4];
    #pragma unroll
    for (int m = 0; m < 4; ++m)
        #pragma unroll
        for (int n = 0; n < 4; ++n)
            acc[m][n] = (f32x4){0.f, 0.f, 0.f, 0.f};

    // staging: thread tid -> LDS byte offset tid*16 (wave-uniform base + lane*16)
    const int sr0 = tid >> 2;              // staging row 0..63
    const int sc0 = (tid & 3) * 8;         // staging col 0,8,16,24
    const short* gA0 = A  + (size_t)(tm + sr0)      * K + sc0;
    const short* gA1 = A  + (size_t)(tm + 64 + sr0) * K + sc0;
    const short* gB0 = Bt + (size_t)(tn + sr0)      * K + sc0;
    const short* gB1 = Bt + (size_t)(tn + 64 + sr0) * K + sc0;
    short* lA0 = lA + sr0 * 32 + sc0;
    short* lA1 = lA + (64 + sr0) * 32 + sc0;
    short* lB0 = lB + sr0 * 32 + sc0;
    short* lB1 = lB + (64 + sr0) * 32 + sc0;

    for (int k0 = 0; k0 < K; k0 += 32) {
        gload16(gA0 + k0, lA0);
        gload16(gA1 + k0, lA1);
        gload16(gB0 + k0, lB0);
        gload16(gB1 + k0, lB1);
        __syncthreads();   // compiler drains vmcnt(0) before s_barrier

        bf8 af[4], bg[4];
        #pragma unroll
        for (int m = 0; m < 4; ++m)
            af[m] = *reinterpret_cast<const bf8*>(lA + (wr + m*16 + fr) * 32 + kg);
        #pragma unroll
        for (int n = 0; n < 4; ++n)
            bg[n] = *reinterpret_cast<const bf8*>(lB + (wc + n*16 + fr) * 32 + kg);

        #pragma unroll
        for (int m = 0; m < 4; ++m)
            #pragma unroll
            for (int n = 0; n < 4; ++n)
                acc[m][n] = __builtin_amdgcn_mfma_f32_16x16x32_bf16(af[m], bg[n], acc[m][n], 0, 0, 0);
        __syncthreads();
    }

    // epilogue: C/D layout col = lane&15, row = (lane>>4)*4 + reg  [verified m89]
    const int rb = (lane >> 4) * 4;
    #pragma unroll
    for (int m = 0; m < 4; ++m) {
        #pragma unroll
        for (int n = 0; n < 4; ++n) {
            const int col = tn + wc + n*16 + fr;
            const float bcol = (EPI == 1) ? bias[col] : 0.f;
            #pragma unroll
            for (int j = 0; j < 4; ++j) {
                const int row = tm + wr + m*16 + rb + j;
                float v = acc[m][n][j];
                if (EPI == 1) v += rs[row] * bcol;
                else          v *= rs[row];
                C[(size_t)row * N + col] = (short)f2bf(v);
            }
        }
    }
}

// ---------------- CSR aggregation:  Y[i] = inv_in[i] * sum_{e: dst=i} X[src[e]] ----------------
// grid: (F/(blockDim*8), N); 8 bf16 cols per thread.
template<int RELU>
__global__ __launch_bounds__(256)
void agg_csr(const short* __restrict__ X, short* __restrict__ Y,
             const int* __restrict__ row_off, const int* __restrict__ esrc,
             const float* __restrict__ inv_in, int F)
{
    const int node = blockIdx.y;
    const int c0 = (blockIdx.x * blockDim.x + threadIdx.x) * 8;
    float acc[8];
    #pragma unroll
    for (int j = 0; j < 8; ++j) acc[j] = 0.f;

    const int beg = row_off[node], end = row_off[node + 1];
    for (int p = beg; p < end; ++p) {
        const int s = esrc[p];
        bf8 x = *reinterpret_cast<const bf8*>(X + (size_t)s * F + c0);
        #pragma unroll
        for (int j = 0; j < 8; ++j) acc[j] += bf2f((unsigned short)x[j]);
    }
    const float sc = inv_in[node];
    bf8 o;
    #pragma unroll
    for (int j = 0; j < 8; ++j) {
        float v = acc[j] * sc;
        if (RELU) v = fmaxf(v, 0.f);
        o[j] = (short)f2bf(v);
    }
    *reinterpret_cast<bf8*>(Y + (size_t)node * F + c0) = o;
}

// ---------------- head: logits = H[4096] . Wl[4096][16] + bl; softmax ----------------
__global__ __launch_bounds__(256)
void k_head(const short* __restrict__ H, const float* __restrict__ Wl,
            const float* __restrict__ bl, float* __restrict__ out)
{
    const int row = blockIdx.x;
    const int tid = threadIdx.x;
    float acc[16];
    #pragma unroll
    for (int c = 0; c < 16; ++c) acc[c] = 0.f;

    for (int k = tid; k < 4096; k += 256) {
        const float x = bf2f((unsigned short)H[(size_t)row * 4096 + k]);
        const float4* w = reinterpret_cast<const float4*>(Wl + (size_t)k * 16);
        float4 w0 = w[0], w1 = w[1], w2 = w[2], w3 = w[3];
        acc[0]  += x * w0.x; acc[1]  += x * w0.y; acc[2]  += x * w0.z; acc[3]  += x * w0.w;
        acc[4]  += x * w1.x; acc[5]  += x * w1.y; acc[6]  += x * w1.z; acc[7]  += x * w1.w;
        acc[8]  += x * w2.x; acc[9]  += x * w2.y; acc[10] += x * w2.z; acc[11] += x * w2.w;
        acc[12] += x * w3.x; acc[13] += x * w3.y; acc[14] += x * w3.z; acc[15] += x * w3.w;
    }
    #pragma unroll
    for (int c = 0; c < 16; ++c)
        for (int off = 32; off; off >>= 1)
            acc[c] += __shfl_down(acc[c], off, 64);

    __shared__ float sm[16][4];
    const int wid = tid >> 6, lane = tid & 63;
    if (lane == 0) {
        #pragma unroll
        for (int c = 0; c < 16; ++c) sm[c][wid] = acc[c];
    }
    __syncthreads();
    if (tid < 16) {
        float l = sm[tid][0] + sm[tid][1] + sm[tid][2] + sm[tid][3] + bl[tid];
        float mx = l;
        #pragma unroll
        for (int off = 1; off < 16; off <<= 1) mx = fmaxf(mx, __shfl_xor(mx, off, 16));
        float e = expf(l - mx);
        float s = e;
        #pragma unroll
        for (int off = 1; off < 16; off <<= 1) s += __shfl_xor(s, off, 16);
        out[(size_t)row * 16 + tid] = e / s;
    }
}

// ---------------- launch ----------------

extern "C" void kernel_launch(void* const* d_in, const int* in_sizes, int n_in,
                              void* d_out, int out_size, void* d_ws, size_t ws_size,
                              hipStream_t stream)
{
    const float* features = (const float*)d_in[0];
    const float* W1       = (const float*)d_in[1];
    const float* b1       = (const float*)d_in[2];
    const float* W2       = (const float*)d_in[3];
    const float* Wl       = (const float*)d_in[4];
    const float* bl       = (const float*)d_in[5];
    const int*   src      = (const int*)d_in[6];
    const int*   dst      = (const int*)d_in[7];
    float* out = (float*)d_out;

    const int N = 4096, IN = 512, H = 8192;
    const int E = in_sizes[6];

    char* ws = (char*)d_ws;
    size_t o = 0;
    auto alloc = [&](size_t bytes) -> char* {
        char* p = ws + o;
        o = (o + bytes + 255) & ~(size_t)255;
        return p;
    };
    short* W2t   = (short*)alloc((size_t)N * H * 2);     // 64 MB  W2^T bf16 [4096][8192]
    short* h1    = (short*)alloc((size_t)N * H * 2);     // 64 MB  conv1 out bf16 [4096][8192]
    short* x2s   = (short*)alloc((size_t)N * N * 2);     // 32 MB  (h1 W2)*inv_out bf16
    short* featb = (short*)alloc((size_t)N * IN * 2);    // 4 MB   features*inv_out bf16
    short* aggF  = (short*)alloc((size_t)N * IN * 2);    // 4 MB   A_hat X bf16
    short* W1t   = (short*)alloc((size_t)H * IN * 2);    // 8 MB   W1^T bf16 [8192][512]
    float* deg_out = (float*)alloc(N * 4);
    float* deg_in  = (float*)alloc(N * 4);
    float* inv_out = (float*)alloc(N * 4);
    float* inv_in  = (float*)alloc(N * 4);
    float* rowsum  = (float*)alloc(N * 4);
    int*   cursor  = (int*)alloc(N * 4);
    int*   row_off = (int*)alloc((N + 1) * 4);
    int*   esrc    = (int*)alloc((size_t)E * 4);
    short* h2 = h1;   // alias: h1 dead after GEMM2, h2 written by agg2

    // graph prep
    k_zero <<<(N + 255) / 256, 256, 0, stream>>>(deg_out, deg_in, cursor, N);
    k_count<<<(E + 255) / 256, 256, 0, stream>>>(src, dst, deg_out, deg_in, E);
    k_inv  <<<(N + 255) / 256, 256, 0, stream>>>(deg_out, deg_in, inv_out, inv_in, N);
    k_scan <<<1, 1024, 0, stream>>>(deg_in, row_off);
    k_fill <<<(E + 255) / 256, 256, 0, stream>>>(src, dst, row_off, cursor, esrc, E);
    k_rowsum<<<N, 64, 0, stream>>>(row_off, esrc, inv_out, inv_in, rowsum);

    // operand conversion
    k_cvt_scale<<<(N * IN / 4 + 255) / 256, 256, 0, stream>>>(features, inv_out, featb,
                                                              N * IN / 4, IN / 4);
    k_tr <<<dim3(H / 32, IN / 32), dim3(32, 8), 0, stream>>>(W1, W1t, IN, H);
    k_tr <<<dim3(N / 32, H / 32), dim3(32, 8), 0, stream>>>(W2, W2t, H, N);

    // conv1: aggregate features first (F=512), then GEMM1 with rowsum*b1 epilogue
    agg_csr<0><<<dim3(1, N), 64, 0, stream>>>(featb, aggF, row_off, esrc, inv_in, IN);
    gemm_bf16<1><<<dim3(H / 128, N / 128), 256, 0, stream>>>(aggF, W1t, h1, b1, rowsum, N, H, IN);

    // conv2: project first, then aggregate
    gemm_bf16<2><<<dim3(N / 128, N / 128), 256, 0, stream>>>(h1, W2t, x2s, nullptr, inv_out, N, N, H);
    agg_csr<1><<<dim3(N / 2048, N), 256, 0, stream>>>(x2s, h2, row_off, esrc, inv_in, N);

    // head + softmax
    k_head<<<N, 256, 0, stream>>>(h2, Wl, bl, out);
}

// Round 4
// 592.123 us; speedup vs baseline: 1.6808x; 1.2494x over previous
//
#include <hip/hip_runtime.h>
#include <cstdint>
#include <cstddef>

// ---------------------------------------------------------------------------
// GCN forward:  softmax( (A_hat relu(A_hat (X W1 + b1) W2)) Wl + bl )
// conv1 reordered: aggregate features (F=512) first, GEMM1 epilogue adds
// rowsum*b1. conv2: project (8192->4096) then aggregate.
// GEMM: 256x128 tile, BK=64, 8 waves (4Mx2N), TRIPLE-buffered LDS (race-free
// t+2 prefetch), global_load_lds w16 with pre-swizzled source + XOR-swizzled
// ds_read (T2), counted vmcnt(6) (T4), 2x16-MFMA phases (T3), setprio (T5).
// R4 fix: staging unit stride is 4096 SHORTS (64x64 bf16 = 8KB), was 8192.
// ---------------------------------------------------------------------------

using bf8   = __attribute__((ext_vector_type(8))) short;   // 8 bf16 (4 VGPR)
using s4    = __attribute__((ext_vector_type(4))) short;
using f32x4 = __attribute__((ext_vector_type(4))) float;

static __device__ __forceinline__ unsigned short f2bf(float f) {
    union { float f; uint32_t u; } v; v.f = f;
    uint32_t r = (v.u + 0x7FFFu + ((v.u >> 16) & 1u)) >> 16;   // RNE
    return (unsigned short)r;
}
static __device__ __forceinline__ float bf2f(unsigned short b) {
    union { uint32_t u; float f; } v; v.u = ((uint32_t)b) << 16;
    return v.f;
}

static __device__ __forceinline__ void gload16(const short* g, short* l) {
    __builtin_amdgcn_global_load_lds(
        (const __attribute__((address_space(1))) unsigned int*)g,
        (__attribute__((address_space(3))) unsigned int*)l,
        16, 0, 0);
}

// ---------------- prep kernels ----------------

__global__ void k_zero(float* a, float* b, int* c, int n) {
    int i = blockIdx.x * blockDim.x + threadIdx.x;
    if (i < n) { a[i] = 0.f; b[i] = 0.f; c[i] = 0; }
}

__global__ void k_count(const int* __restrict__ src, const int* __restrict__ dst,
                        float* deg_out, float* deg_in, int E) {
    int e = blockIdx.x * blockDim.x + threadIdx.x;
    if (e < E) {
        atomicAdd(&deg_out[src[e]], 1.f);
        atomicAdd(&deg_in[dst[e]], 1.f);
    }
}

__global__ void k_inv(const float* deg_out, const float* deg_in,
                      float* inv_out, float* inv_in, int n) {
    int i = blockIdx.x * blockDim.x + threadIdx.x;
    if (i < n) {
        inv_out[i] = rsqrtf(fmaxf(deg_out[i], 1.f));
        inv_in[i]  = rsqrtf(fmaxf(deg_in[i], 1.f));
    }
}

__global__ void k_scan(const float* __restrict__ deg_in, int* __restrict__ row_off) {
    __shared__ int part[1024];
    const int t = threadIdx.x;
    int v0 = (int)deg_in[t*4+0], v1 = (int)deg_in[t*4+1],
        v2 = (int)deg_in[t*4+2], v3 = (int)deg_in[t*4+3];
    part[t] = v0 + v1 + v2 + v3;
    __syncthreads();
    for (int off = 1; off < 1024; off <<= 1) {
        int x = (t >= off) ? part[t - off] : 0;
        __syncthreads();
        part[t] += x;
        __syncthreads();
    }
    int run = (t == 0) ? 0 : part[t-1];
    row_off[t*4+0] = run; run += v0;
    row_off[t*4+1] = run; run += v1;
    row_off[t*4+2] = run; run += v2;
    row_off[t*4+3] = run; run += v3;
    if (t == 1023) row_off[4096] = run;
}

__global__ void k_fill(const int* __restrict__ src, const int* __restrict__ dst,
                       const int* __restrict__ row_off, int* cursor,
                       int* __restrict__ esrc, int E) {
    int e = blockIdx.x * blockDim.x + threadIdx.x;
    if (e < E) {
        int d = dst[e];
        int p = atomicAdd(&cursor[d], 1);
        esrc[row_off[d] + p] = src[e];
    }
}

__global__ void k_rowsum(const int* __restrict__ row_off, const int* __restrict__ esrc,
                         const float* __restrict__ inv_out, const float* __restrict__ inv_in,
                         float* __restrict__ rowsum) {
    const int node = blockIdx.x, lane = threadIdx.x;
    const int beg = row_off[node], end = row_off[node + 1];
    float s = 0.f;
    for (int p = beg + lane; p < end; p += 64) s += inv_out[esrc[p]];
    #pragma unroll
    for (int off = 32; off; off >>= 1) s += __shfl_down(s, off, 64);
    if (lane == 0) rowsum[node] = s * inv_in[node];
}

__global__ void k_cvt_scale(const float* __restrict__ in, const float* __restrict__ sc,
                            short* __restrict__ out, int n4, int f4) {
    int i = blockIdx.x * blockDim.x + threadIdx.x;
    if (i < n4) {
        const float s = sc[i / f4];
        float4 v = reinterpret_cast<const float4*>(in)[i];
        s4 o;
        o[0] = (short)f2bf(v.x * s); o[1] = (short)f2bf(v.y * s);
        o[2] = (short)f2bf(v.z * s); o[3] = (short)f2bf(v.w * s);
        reinterpret_cast<s4*>(out)[i] = o;
    }
}

// fp32 [R][C] -> bf16 [C][R]; 64(r)x32(c) tile, block (32,8), ushort2 writes
__global__ void k_tr2(const float* __restrict__ in, short* __restrict__ out, int R, int C) {
    __shared__ float tile[64][33];
    const int bc = blockIdx.x * 32, br = blockIdx.y * 64;
    const int tx = threadIdx.x, ty = threadIdx.y;
    #pragma unroll
    for (int dy = 0; dy < 64; dy += 8)
        tile[ty + dy][tx] = in[(size_t)(br + ty + dy) * C + bc + tx];
    __syncthreads();
    #pragma unroll
    for (int dy = 0; dy < 32; dy += 8) {
        const int oy = ty + dy;
        ushort2 o;
        o.x = f2bf(tile[tx * 2][oy]);
        o.y = f2bf(tile[tx * 2 + 1][oy]);
        *reinterpret_cast<ushort2*>(&out[(size_t)(bc + oy) * R + br + tx * 2]) = o;
    }
}

// ---------------- bf16 MFMA GEMM, phase-split pipeline ----------------
// C[M][N] = A[M][K] * Bt^T; A row-major, Bt = B^T row-major [N][K], all bf16.
// EPI==1: out = acc + rs[row]*bias[col]; EPI==2: out = acc * rs[row].
// Tile 256(M) x 128(N), BK=64. 8 waves = 4M x 2N, wave tile 64x64 (4x4 frags).
// LDS: 3 buffers x (A[256][64] + B[128][64]) bf16 = 3 x 48KB = 144KB.
// Staging: 6 units/tile, each 64rows x 64cols bf16 = 4096 shorts = 8KB
// (512thr x 16B). Linear LDS dest (tid*16B within unit), source chunk
// pre-swizzled cs = cq ^ (row&7); ds_read applies the same XOR (rule #21).
// Per K-tile: 2 phases x {ds_read frags, 3 stage units (tile t+2 -> buffer
// c2, never concurrently read), barrier, lgkmcnt(0), 16 MFMA, barrier};
// vmcnt(6) once per tile (next tile's 6 units in flight), vmcnt(0) at tail.
// Requires nt >= 2 and M%256==N%128==K%64==0.
template<int EPI>
__global__ __launch_bounds__(512, 2)
void gemm8p(const short* __restrict__ A, const short* __restrict__ Bt,
            short* __restrict__ C,
            const float* __restrict__ bias, const float* __restrict__ rs,
            int M, int N, int K)
{
    constexpr int USZ  = 4096;            // shorts per 64x64 staging unit
    constexpr int BOFF = 4 * USZ;         // B region offset within buffer (16384)
    constexpr int BUF  = 6 * USZ;         // shorts per buffer (24576 = 48KB)
    __shared__ __align__(16) short lds[3 * BUF];   // 144 KB
    const int tid  = threadIdx.x;
    const int wid  = tid >> 6, lane = tid & 63;
    const int wm   = wid >> 1;            // 0..3  (M wave index)
    const int wn   = wid & 1;             // 0..1  (N wave index)
    const int fr   = lane & 15;
    const int kq   = lane >> 4;           // 0..3
    const int tm   = blockIdx.y * 256;
    const int tn   = blockIdx.x * 128;
    const int nt   = K >> 6;

    // ---- staging addressing (per thread: 1 gload16 per 8KB unit) ----
    const int srow = tid >> 3;            // 0..63 row within unit
    const int scq  = tid & 7;             // linear 16B-chunk within row
    const int scs  = scq ^ (srow & 7);    // pre-swizzled source chunk
    const short* gA = A  + (size_t)(tm + srow) * K + scs * 8;
    const short* gB = Bt + (size_t)(tn + srow) * K + scs * 8;
    short* const ldst = lds + tid * 8;    // + bufoff + unit*USZ (shorts)

    // ---- fragment read offsets (shorts, lane-constant) ----
    // frag (row r, k-slice s): chunk (s*4+kq) ^ (r&7); r&7 == fr&7 here.
    const int cx0 = (0 * 4 + kq) ^ (fr & 7);
    const int cx1 = (1 * 4 + kq) ^ (fr & 7);
    int aoff[4][2], boff[4][2];
    #pragma unroll
    for (int mi = 0; mi < 4; ++mi) {
        const int r = wm * 64 + mi * 16 + fr;
        aoff[mi][0] = r * 64 + cx0 * 8;
        aoff[mi][1] = r * 64 + cx1 * 8;
    }
    #pragma unroll
    for (int n = 0; n < 4; ++n) {
        const int r = wn * 64 + n * 16 + fr;
        boff[n][0] = BOFF + r * 64 + cx0 * 8;
        boff[n][1] = BOFF + r * 64 + cx1 * 8;
    }

    f32x4 acc[4][4];
    #pragma unroll
    for (int mi = 0; mi < 4; ++mi)
        #pragma unroll
        for (int n = 0; n < 4; ++n)
            acc[mi][n] = (f32x4){0.f, 0.f, 0.f, 0.f};

    int c0 = 0, c1 = BUF, c2 = 2 * BUF;   // buffer offsets in shorts

    // ---- prologue: stage tiles 0 (->c0) and 1 (->c1); drain tile 0 ----
    #pragma unroll
    for (int u = 0; u < 4; ++u) gload16(gA + (size_t)u * 64 * K,      ldst + c0 + u * USZ);
    #pragma unroll
    for (int v = 0; v < 2; ++v) gload16(gB + (size_t)v * 64 * K,      ldst + c0 + BOFF + v * USZ);
    #pragma unroll
    for (int u = 0; u < 4; ++u) gload16(gA + (size_t)u * 64 * K + 64, ldst + c1 + u * USZ);
    #pragma unroll
    for (int v = 0; v < 2; ++v) gload16(gB + (size_t)v * 64 * K + 64, ldst + c1 + BOFF + v * USZ);
    asm volatile("s_waitcnt vmcnt(6)" ::: "memory");
    __builtin_amdgcn_sched_barrier(0);
    __builtin_amdgcn_s_barrier();

    for (int t = 0; t < nt; ++t) {
        const bool pf = (t + 2 < nt);
        const size_t kf = (size_t)(t + 2) * 64;   // k offset of prefetch tile

        // ---------------- phase 0: m-frags 0,1 x all n ----------------
        bf8 a0[2][2], b0[4][2];
        #pragma unroll
        for (int mi = 0; mi < 2; ++mi)
            #pragma unroll
            for (int s = 0; s < 2; ++s)
                a0[mi][s] = *reinterpret_cast<const bf8*>(lds + c0 + aoff[mi][s]);
        #pragma unroll
        for (int n = 0; n < 4; ++n)
            #pragma unroll
            for (int s = 0; s < 2; ++s)
                b0[n][s] = *reinterpret_cast<const bf8*>(lds + c0 + boff[n][s]);
        if (pf) {
            gload16(gA + (size_t)0 * 64 * K + kf, ldst + c2 + 0 * USZ);
            gload16(gA + (size_t)1 * 64 * K + kf, ldst + c2 + 1 * USZ);
            gload16(gA + (size_t)2 * 64 * K + kf, ldst + c2 + 2 * USZ);
        }
        __builtin_amdgcn_s_barrier();
        asm volatile("s_waitcnt lgkmcnt(0)" ::: "memory");
        __builtin_amdgcn_sched_barrier(0);
        __builtin_amdgcn_s_setprio(1);
        #pragma unroll
        for (int mi = 0; mi < 2; ++mi)
            #pragma unroll
            for (int n = 0; n < 4; ++n)
                #pragma unroll
                for (int s = 0; s < 2; ++s)
                    acc[mi][n] = __builtin_amdgcn_mfma_f32_16x16x32_bf16(a0[mi][s], b0[n][s], acc[mi][n], 0, 0, 0);
        __builtin_amdgcn_s_setprio(0);
        __builtin_amdgcn_s_barrier();

        // ---------------- phase 1: m-frags 2,3 x all n ----------------
        bf8 a1[2][2];
        #pragma unroll
        for (int mi = 0; mi < 2; ++mi)
            #pragma unroll
            for (int s = 0; s < 2; ++s)
                a1[mi][s] = *reinterpret_cast<const bf8*>(lds + c0 + aoff[2 + mi][s]);
        if (pf) {
            gload16(gA + (size_t)3 * 64 * K + kf, ldst + c2 + 3 * USZ);
            gload16(gB + (size_t)0 * 64 * K + kf, ldst + c2 + BOFF + 0 * USZ);
            gload16(gB + (size_t)1 * 64 * K + kf, ldst + c2 + BOFF + 1 * USZ);
        }
        __builtin_amdgcn_s_barrier();
        asm volatile("s_waitcnt lgkmcnt(0)" ::: "memory");
        __builtin_amdgcn_sched_barrier(0);
        __builtin_amdgcn_s_setprio(1);
        #pragma unroll
        for (int mi = 0; mi < 2; ++mi)
            #pragma unroll
            for (int n = 0; n < 4; ++n)
                #pragma unroll
                for (int s = 0; s < 2; ++s)
                    acc[2 + mi][n] = __builtin_amdgcn_mfma_f32_16x16x32_bf16(a1[mi][s], b0[n][s], acc[2 + mi][n], 0, 0, 0);
        __builtin_amdgcn_s_setprio(0);
        if (pf) { asm volatile("s_waitcnt vmcnt(6)" ::: "memory"); }
        else    { asm volatile("s_waitcnt vmcnt(0)" ::: "memory"); }
        __builtin_amdgcn_sched_barrier(0);
        __builtin_amdgcn_s_barrier();

        const int tmp = c0; c0 = c1; c1 = c2; c2 = tmp;
    }

    // ---- epilogue: C/D layout col = lane&15, row = (lane>>4)*4 + reg ----
    const int rb = kq * 4;
    #pragma unroll
    for (int mi = 0; mi < 4; ++mi) {
        #pragma unroll
        for (int n = 0; n < 4; ++n) {
            const int col = tn + wn * 64 + n * 16 + fr;
            const float bcol = (EPI == 1) ? bias[col] : 0.f;
            #pragma unroll
            for (int j = 0; j < 4; ++j) {
                const int row = tm + wm * 64 + mi * 16 + rb + j;
                float v = acc[mi][n][j];
                if (EPI == 1) v += rs[row] * bcol;
                else          v *= rs[row];
                C[(size_t)row * N + col] = (short)f2bf(v);
            }
        }
    }
}

// ---------------- CSR aggregation:  Y[i] = inv_in[i] * sum_{e: dst=i} X[src[e]] ----------------
template<int RELU>
__global__ __launch_bounds__(256)
void agg_csr(const short* __restrict__ X, short* __restrict__ Y,
             const int* __restrict__ row_off, const int* __restrict__ esrc,
             const float* __restrict__ inv_in, int F)
{
    const int node = blockIdx.y;
    const int c0 = (blockIdx.x * blockDim.x + threadIdx.x) * 8;
    float acc[8];
    #pragma unroll
    for (int j = 0; j < 8; ++j) acc[j] = 0.f;

    const int beg = row_off[node], end = row_off[node + 1];
    int p = beg;
    for (; p + 1 < end; p += 2) {
        const int s0 = esrc[p], s1 = esrc[p + 1];
        bf8 x0 = *reinterpret_cast<const bf8*>(X + (size_t)s0 * F + c0);
        bf8 x1 = *reinterpret_cast<const bf8*>(X + (size_t)s1 * F + c0);
        #pragma unroll
        for (int j = 0; j < 8; ++j)
            acc[j] += bf2f((unsigned short)x0[j]) + bf2f((unsigned short)x1[j]);
    }
    if (p < end) {
        const int s0 = esrc[p];
        bf8 x0 = *reinterpret_cast<const bf8*>(X + (size_t)s0 * F + c0);
        #pragma unroll
        for (int j = 0; j < 8; ++j) acc[j] += bf2f((unsigned short)x0[j]);
    }
    const float sc = inv_in[node];
    bf8 o;
    #pragma unroll
    for (int j = 0; j < 8; ++j) {
        float v = acc[j] * sc;
        if (RELU) v = fmaxf(v, 0.f);
        o[j] = (short)f2bf(v);
    }
    *reinterpret_cast<bf8*>(Y + (size_t)node * F + c0) = o;
}

// ---------------- head: logits = H[4096] . Wl[4096][16] + bl; softmax ----------------
__global__ __launch_bounds__(256)
void k_head(const short* __restrict__ H, const float* __restrict__ Wl,
            const float* __restrict__ bl, float* __restrict__ out)
{
    const int row = blockIdx.x;
    const int tid = threadIdx.x;
    float acc[16];
    #pragma unroll
    for (int c = 0; c < 16; ++c) acc[c] = 0.f;

    for (int k = tid; k < 4096; k += 256) {
        const float x = bf2f((unsigned short)H[(size_t)row * 4096 + k]);
        const float4* w = reinterpret_cast<const float4*>(Wl + (size_t)k * 16);
        float4 w0 = w[0], w1 = w[1], w2 = w[2], w3 = w[3];
        acc[0]  += x * w0.x; acc[1]  += x * w0.y; acc[2]  += x * w0.z; acc[3]  += x * w0.w;
        acc[4]  += x * w1.x; acc[5]  += x * w1.y; acc[6]  += x * w1.z; acc[7]  += x * w1.w;
        acc[8]  += x * w2.x; acc[9]  += x * w2.y; acc[10] += x * w2.z; acc[11] += x * w2.w;
        acc[12] += x * w3.x; acc[13] += x * w3.y; acc[14] += x * w3.z; acc[15] += x * w3.w;
    }
    #pragma unroll
    for (int c = 0; c < 16; ++c)
        for (int off = 32; off; off >>= 1)
            acc[c] += __shfl_down(acc[c], off, 64);

    __shared__ float sm[16][4];
    const int wid = tid >> 6, lane = tid & 63;
    if (lane == 0) {
        #pragma unroll
        for (int c = 0; c < 16; ++c) sm[c][wid] = acc[c];
    }
    __syncthreads();
    if (tid < 16) {
        float l = sm[tid][0] + sm[tid][1] + sm[tid][2] + sm[tid][3] + bl[tid];
        float mx = l;
        #pragma unroll
        for (int off = 1; off < 16; off <<= 1) mx = fmaxf(mx, __shfl_xor(mx, off, 16));
        float e = expf(l - mx);
        float s = e;
        #pragma unroll
        for (int off = 1; off < 16; off <<= 1) s += __shfl_xor(s, off, 16);
        out[(size_t)row * 16 + tid] = e / s;
    }
}

// ---------------- launch ----------------

extern "C" void kernel_launch(void* const* d_in, const int* in_sizes, int n_in,
                              void* d_out, int out_size, void* d_ws, size_t ws_size,
                              hipStream_t stream)
{
    const float* features = (const float*)d_in[0];
    const float* W1       = (const float*)d_in[1];
    const float* b1       = (const float*)d_in[2];
    const float* W2       = (const float*)d_in[3];
    const float* Wl       = (const float*)d_in[4];
    const float* bl       = (const float*)d_in[5];
    const int*   src      = (const int*)d_in[6];
    const int*   dst      = (const int*)d_in[7];
    float* out = (float*)d_out;

    const int N = 4096, IN = 512, H = 8192;
    const int E = in_sizes[6];

    char* ws = (char*)d_ws;
    size_t o = 0;
    auto alloc = [&](size_t bytes) -> char* {
        char* p = ws + o;
        o = (o + bytes + 255) & ~(size_t)255;
        return p;
    };
    short* W2t   = (short*)alloc((size_t)N * H * 2);     // 64 MB  W2^T bf16 [4096][8192]
    short* h1    = (short*)alloc((size_t)N * H * 2);     // 64 MB  conv1 out bf16 [4096][8192]
    short* x2s   = (short*)alloc((size_t)N * N * 2);     // 32 MB  (h1 W2)*inv_out bf16
    short* featb = (short*)alloc((size_t)N * IN * 2);    // 4 MB   features*inv_out bf16
    short* aggF  = (short*)alloc((size_t)N * IN * 2);    // 4 MB   A_hat X bf16
    short* W1t   = (short*)alloc((size_t)H * IN * 2);    // 8 MB   W1^T bf16 [8192][512]
    float* deg_out = (float*)alloc(N * 4);
    float* deg_in  = (float*)alloc(N * 4);
    float* inv_out = (float*)alloc(N * 4);
    float* inv_in  = (float*)alloc(N * 4);
    float* rowsum  = (float*)alloc(N * 4);
    int*   cursor  = (int*)alloc(N * 4);
    int*   row_off = (int*)alloc((N + 1) * 4);
    int*   esrc    = (int*)alloc((size_t)E * 4);
    short* h2 = h1;   // alias: h1 dead after GEMM2, h2 written by agg2

    // graph prep
    k_zero <<<(N + 255) / 256, 256, 0, stream>>>(deg_out, deg_in, cursor, N);
    k_count<<<(E + 255) / 256, 256, 0, stream>>>(src, dst, deg_out, deg_in, E);
    k_inv  <<<(N + 255) / 256, 256, 0, stream>>>(deg_out, deg_in, inv_out, inv_in, N);
    k_scan <<<1, 1024, 0, stream>>>(deg_in, row_off);
    k_fill <<<(E + 255) / 256, 256, 0, stream>>>(src, dst, row_off, cursor, esrc, E);
    k_rowsum<<<N, 64, 0, stream>>>(row_off, esrc, inv_out, inv_in, rowsum);

    // operand conversion
    k_cvt_scale<<<(N * IN / 4 + 255) / 256, 256, 0, stream>>>(features, inv_out, featb,
                                                              N * IN / 4, IN / 4);
    k_tr2<<<dim3(H / 32, IN / 64), dim3(32, 8), 0, stream>>>(W1, W1t, IN, H);
    k_tr2<<<dim3(N / 32, H / 64), dim3(32, 8), 0, stream>>>(W2, W2t, H, N);

    // conv1: aggregate features first (F=512), then GEMM1 with rowsum*b1 epilogue
    agg_csr<0><<<dim3(1, N), 64, 0, stream>>>(featb, aggF, row_off, esrc, inv_in, IN);
    gemm8p<1><<<dim3(H / 128, N / 256), 512, 0, stream>>>(aggF, W1t, h1, b1, rowsum, N, H, IN);

    // conv2: project first, then aggregate
    gemm8p<2><<<dim3(N / 128, N / 256), 512, 0, stream>>>(h1, W2t, x2s, nullptr, inv_out, N, N, H);
    agg_csr<1><<<dim3(N / 2048, N), 256, 0, stream>>>(x2s, h2, row_off, esrc, inv_in, N);

    // head + softmax
    k_head<<<N, 256, 0, stream>>>(h2, Wl, bl, out);
}

// Round 5
// 549.904 us; speedup vs baseline: 1.8098x; 1.0768x over previous
//
#include <hip/hip_runtime.h>
#include <cstdint>
#include <cstddef>

// ---------------------------------------------------------------------------
// GCN forward:  softmax( (A_hat relu(A_hat (X W1 + b1) W2)) Wl + bl )
// conv1 reordered: aggregate features (F=512) first, GEMM1 epilogue adds
// rowsum*b1. conv2: project (8192->4096) then aggregate.
// GEMM (R5): 256x256 tile, BK=64, 8 waves (2M x 4N), wave tile 128x64,
// double-buffered LDS (128KB), aged-drain staging (issue all 8 units of
// tile t+1 in phases 0-1 of tile t, single vmcnt(0) at end of phase 2),
// 3 fine phases/K-tile (16/16/32 MFMA), T2 XOR swizzle (both sides),
// T5 setprio, bijective XCD-chunk swizzle.
// ---------------------------------------------------------------------------

using bf8   = __attribute__((ext_vector_type(8))) short;   // 8 bf16 (4 VGPR)
using s4    = __attribute__((ext_vector_type(4))) short;
using f32x4 = __attribute__((ext_vector_type(4))) float;

static __device__ __forceinline__ unsigned short f2bf(float f) {
    union { float f; uint32_t u; } v; v.f = f;
    uint32_t r = (v.u + 0x7FFFu + ((v.u >> 16) & 1u)) >> 16;   // RNE
    return (unsigned short)r;
}
static __device__ __forceinline__ float bf2f(unsigned short b) {
    union { uint32_t u; float f; } v; v.u = ((uint32_t)b) << 16;
    return v.f;
}

static __device__ __forceinline__ void gload16(const short* g, short* l) {
    __builtin_amdgcn_global_load_lds(
        (const __attribute__((address_space(1))) unsigned int*)g,
        (__attribute__((address_space(3))) unsigned int*)l,
        16, 0, 0);
}

// ---------------- prep kernels ----------------

__global__ void k_zero(float* a, float* b, int* c, int n) {
    int i = blockIdx.x * blockDim.x + threadIdx.x;
    if (i < n) { a[i] = 0.f; b[i] = 0.f; c[i] = 0; }
}

__global__ void k_count(const int* __restrict__ src, const int* __restrict__ dst,
                        float* deg_out, float* deg_in, int E) {
    int e = blockIdx.x * blockDim.x + threadIdx.x;
    if (e < E) {
        atomicAdd(&deg_out[src[e]], 1.f);
        atomicAdd(&deg_in[dst[e]], 1.f);
    }
}

__global__ void k_inv(const float* deg_out, const float* deg_in,
                      float* inv_out, float* inv_in, int n) {
    int i = blockIdx.x * blockDim.x + threadIdx.x;
    if (i < n) {
        inv_out[i] = rsqrtf(fmaxf(deg_out[i], 1.f));
        inv_in[i]  = rsqrtf(fmaxf(deg_in[i], 1.f));
    }
}

__global__ void k_scan(const float* __restrict__ deg_in, int* __restrict__ row_off) {
    __shared__ int part[1024];
    const int t = threadIdx.x;
    int v0 = (int)deg_in[t*4+0], v1 = (int)deg_in[t*4+1],
        v2 = (int)deg_in[t*4+2], v3 = (int)deg_in[t*4+3];
    part[t] = v0 + v1 + v2 + v3;
    __syncthreads();
    for (int off = 1; off < 1024; off <<= 1) {
        int x = (t >= off) ? part[t - off] : 0;
        __syncthreads();
        part[t] += x;
        __syncthreads();
    }
    int run = (t == 0) ? 0 : part[t-1];
    row_off[t*4+0] = run; run += v0;
    row_off[t*4+1] = run; run += v1;
    row_off[t*4+2] = run; run += v2;
    row_off[t*4+3] = run; run += v3;
    if (t == 1023) row_off[4096] = run;
}

__global__ void k_fill(const int* __restrict__ src, const int* __restrict__ dst,
                       const int* __restrict__ row_off, int* cursor,
                       int* __restrict__ esrc, int E) {
    int e = blockIdx.x * blockDim.x + threadIdx.x;
    if (e < E) {
        int d = dst[e];
        int p = atomicAdd(&cursor[d], 1);
        esrc[row_off[d] + p] = src[e];
    }
}

__global__ void k_rowsum(const int* __restrict__ row_off, const int* __restrict__ esrc,
                         const float* __restrict__ inv_out, const float* __restrict__ inv_in,
                         float* __restrict__ rowsum) {
    const int node = blockIdx.x, lane = threadIdx.x;
    const int beg = row_off[node], end = row_off[node + 1];
    float s = 0.f;
    for (int p = beg + lane; p < end; p += 64) s += inv_out[esrc[p]];
    #pragma unroll
    for (int off = 32; off; off >>= 1) s += __shfl_down(s, off, 64);
    if (lane == 0) rowsum[node] = s * inv_in[node];
}

__global__ void k_cvt_scale(const float* __restrict__ in, const float* __restrict__ sc,
                            short* __restrict__ out, int n4, int f4) {
    int i = blockIdx.x * blockDim.x + threadIdx.x;
    if (i < n4) {
        const float s = sc[i / f4];
        float4 v = reinterpret_cast<const float4*>(in)[i];
        s4 o;
        o[0] = (short)f2bf(v.x * s); o[1] = (short)f2bf(v.y * s);
        o[2] = (short)f2bf(v.z * s); o[3] = (short)f2bf(v.w * s);
        reinterpret_cast<s4*>(out)[i] = o;
    }
}

// fp32 [R][C] -> bf16 [C][R]; 64(r)x32(c) tile, block (32,8), ushort2 writes
__global__ void k_tr2(const float* __restrict__ in, short* __restrict__ out, int R, int C) {
    __shared__ float tile[64][33];
    const int bc = blockIdx.x * 32, br = blockIdx.y * 64;
    const int tx = threadIdx.x, ty = threadIdx.y;
    #pragma unroll
    for (int dy = 0; dy < 64; dy += 8)
        tile[ty + dy][tx] = in[(size_t)(br + ty + dy) * C + bc + tx];
    __syncthreads();
    #pragma unroll
    for (int dy = 0; dy < 32; dy += 8) {
        const int oy = ty + dy;
        ushort2 o;
        o.x = f2bf(tile[tx * 2][oy]);
        o.y = f2bf(tile[tx * 2 + 1][oy]);
        *reinterpret_cast<ushort2*>(&out[(size_t)(bc + oy) * R + br + tx * 2]) = o;
    }
}

// ---------------- bf16 MFMA GEMM, 3-phase fine-interleaved pipeline ----------------
// C[M][N] = A[M][K] * Bt^T; A row-major, Bt = B^T row-major [N][K], all bf16.
// EPI==1: out = acc + rs[row]*bias[col]; EPI==2: out = acc * rs[row].
// Tile 256x256, BK=64. 8 waves = 2M x 4N, wave tile 128x64: 8 m-frags x
// 4 n-frags x 2 k-slices = 64 MFMA/K-tile/wave.
// LDS: 2 buffers x (A[256][64] + B[256][64]) bf16 = 2 x 64KB = 128KB.
// Staging: 8 units/tile of 8KB (64 rows x 8 chunks of 16B; 512 thr x 16B),
// linear LDS dest, source chunk pre-swizzled cs = cq ^ (row&7); ds_read
// applies the same XOR (rule #21). All 8 units of tile t+1 issue in phases
// 0-1 of tile t ("aged drain": the single vmcnt(0) at end of phase 2 is
// ~1.5 phases after last issue). Per K-tile, 3 phases:
//   P0: ds A[0-3]x2 + B[0-1]x2, stage 4 A-units, bar, lgkm0, 16 MFMA, bar
//   P1: ds B[2-3]x2,            stage 4 B-units, bar, lgkm0, 16 MFMA, bar
//   P2: ds A[4-7]x2,                             bar, lgkm0, 32 MFMA,
//       vmcnt(0) (if staged), bar
// Requires nt >= 2 and M%256==N%256==K%64==0; grid nwg%8==0 (XCD swizzle).
template<int EPI>
__global__ __launch_bounds__(512, 2)
void gemm8p(const short* __restrict__ A, const short* __restrict__ Bt,
            short* __restrict__ C,
            const float* __restrict__ bias, const float* __restrict__ rs,
            int M, int N, int K)
{
    constexpr int USZ  = 4096;            // shorts per 64-row x 64-short unit
    constexpr int BOFF = 4 * USZ;         // B region offset within buffer (16384)
    constexpr int BUF  = 8 * USZ;         // shorts per buffer (32768 = 64KB)
    __shared__ __align__(16) short lds[2 * BUF];   // 128 KB
    const int tid  = threadIdx.x;
    const int wid  = tid >> 6, lane = tid & 63;
    const int wm   = wid >> 2;            // 0..1  (M wave index)
    const int wn   = wid & 3;             // 0..3  (N wave index)
    const int fr   = lane & 15;
    const int kq   = lane >> 4;           // 0..3
    const int nt   = K >> 6;

    // bijective XCD-chunk swizzle (nwg % 8 == 0): XCD x owns contiguous tiles
    const int gx  = gridDim.x;
    const int nwg = gx * gridDim.y;
    int bid = blockIdx.y * gx + blockIdx.x;
    bid = (bid & 7) * (nwg >> 3) + (bid >> 3);
    const int tm = (bid / gx) * 256;
    const int tn = (bid % gx) * 256;

    // ---- staging addressing (per thread: 1 gload16 per 8KB unit) ----
    const int srow = tid >> 3;            // 0..63 row within unit
    const int scq  = tid & 7;             // linear 16B-chunk within row
    const int scs  = scq ^ (srow & 7);    // pre-swizzled source chunk
    const short* gA = A  + (size_t)(tm + srow) * K + scs * 8;
    const short* gB = Bt + (size_t)(tn + srow) * K + scs * 8;
    short* const ldst = lds + tid * 8;    // + bufoff + unit*USZ (shorts)

    // ---- fragment read offsets (shorts, lane-constant) ----
    // frag (row r, k-slice s): chunk (s*4+kq) ^ (r&7); r&7 == fr&7 here.
    const int cx0 = (0 * 4 + kq) ^ (fr & 7);
    const int cx1 = (1 * 4 + kq) ^ (fr & 7);
    int aoff[8][2], boff[4][2];
    #pragma unroll
    for (int mi = 0; mi < 8; ++mi) {
        const int r = wm * 128 + mi * 16 + fr;
        aoff[mi][0] = r * 64 + cx0 * 8;
        aoff[mi][1] = r * 64 + cx1 * 8;
    }
    #pragma unroll
    for (int n = 0; n < 4; ++n) {
        const int r = wn * 64 + n * 16 + fr;
        boff[n][0] = BOFF + r * 64 + cx0 * 8;
        boff[n][1] = BOFF + r * 64 + cx1 * 8;
    }

    f32x4 acc[8][4];
    #pragma unroll
    for (int mi = 0; mi < 8; ++mi)
        #pragma unroll
        for (int n = 0; n < 4; ++n)
            acc[mi][n] = (f32x4){0.f, 0.f, 0.f, 0.f};

    // ---- prologue: stage tile 0 -> buf 0; drain ----
    #pragma unroll
    for (int u = 0; u < 4; ++u) gload16(gA + (size_t)u * 64 * K, ldst + u * USZ);
    #pragma unroll
    for (int v = 0; v < 4; ++v) gload16(gB + (size_t)v * 64 * K, ldst + BOFF + v * USZ);
    asm volatile("s_waitcnt vmcnt(0)" ::: "memory");
    __builtin_amdgcn_sched_barrier(0);
    __builtin_amdgcn_s_barrier();

    for (int t = 0; t < nt; ++t) {
        const int cc = (t & 1) * BUF;          // compute buffer
        const int cp = ((t + 1) & 1) * BUF;    // prefetch buffer
        const bool pf = (t + 1 < nt);
        const size_t kf = (size_t)(t + 1) * 64;

        bf8 af[4][2], bg[4][2];

        // ---------------- phase 0: m 0-3 x n 0-1 ----------------
        #pragma unroll
        for (int mi = 0; mi < 4; ++mi)
            #pragma unroll
            for (int s = 0; s < 2; ++s)
                af[mi][s] = *reinterpret_cast<const bf8*>(lds + cc + aoff[mi][s]);
        #pragma unroll
        for (int n = 0; n < 2; ++n)
            #pragma unroll
            for (int s = 0; s < 2; ++s)
                bg[n][s] = *reinterpret_cast<const bf8*>(lds + cc + boff[n][s]);
        if (pf) {
            #pragma unroll
            for (int u = 0; u < 4; ++u)
                gload16(gA + (size_t)u * 64 * K + kf, ldst + cp + u * USZ);
        }
        __builtin_amdgcn_s_barrier();
        asm volatile("s_waitcnt lgkmcnt(0)" ::: "memory");
        __builtin_amdgcn_sched_barrier(0);
        __builtin_amdgcn_s_setprio(1);
        #pragma unroll
        for (int mi = 0; mi < 4; ++mi)
            #pragma unroll
            for (int n = 0; n < 2; ++n)
                #pragma unroll
                for (int s = 0; s < 2; ++s)
                    acc[mi][n] = __builtin_amdgcn_mfma_f32_16x16x32_bf16(af[mi][s], bg[n][s], acc[mi][n], 0, 0, 0);
        __builtin_amdgcn_s_setprio(0);
        __builtin_amdgcn_s_barrier();

        // ---------------- phase 1: m 0-3 x n 2-3 ----------------
        #pragma unroll
        for (int n = 2; n < 4; ++n)
            #pragma unroll
            for (int s = 0; s < 2; ++s)
                bg[n][s] = *reinterpret_cast<const bf8*>(lds + cc + boff[n][s]);
        if (pf) {
            #pragma unroll
            for (int v = 0; v < 4; ++v)
                gload16(gB + (size_t)v * 64 * K + kf, ldst + cp + BOFF + v * USZ);
        }
        __builtin_amdgcn_s_barrier();
        asm volatile("s_waitcnt lgkmcnt(0)" ::: "memory");
        __builtin_amdgcn_sched_barrier(0);
        __builtin_amdgcn_s_setprio(1);
        #pragma unroll
        for (int mi = 0; mi < 4; ++mi)
            #pragma unroll
            for (int n = 2; n < 4; ++n)
                #pragma unroll
                for (int s = 0; s < 2; ++s)
                    acc[mi][n] = __builtin_amdgcn_mfma_f32_16x16x32_bf16(af[mi][s], bg[n][s], acc[mi][n], 0, 0, 0);
        __builtin_amdgcn_s_setprio(0);
        __builtin_amdgcn_s_barrier();

        // ---------------- phase 2: m 4-7 x all n ----------------
        #pragma unroll
        for (int mi = 0; mi < 4; ++mi)
            #pragma unroll
            for (int s = 0; s < 2; ++s)
                af[mi][s] = *reinterpret_cast<const bf8*>(lds + cc + aoff[4 + mi][s]);
        __builtin_amdgcn_s_barrier();
        asm volatile("s_waitcnt lgkmcnt(0)" ::: "memory");
        __builtin_amdgcn_sched_barrier(0);
        __builtin_amdgcn_s_setprio(1);
        #pragma unroll
        for (int mi = 0; mi < 4; ++mi)
            #pragma unroll
            for (int n = 0; n < 4; ++n)
                #pragma unroll
                for (int s = 0; s < 2; ++s)
                    acc[4 + mi][n] = __builtin_amdgcn_mfma_f32_16x16x32_bf16(af[mi][s], bg[n][s], acc[4 + mi][n], 0, 0, 0);
        __builtin_amdgcn_s_setprio(0);
        if (pf) {
            asm volatile("s_waitcnt vmcnt(0)" ::: "memory");   // aged drain (~1.5 phases old)
            __builtin_amdgcn_sched_barrier(0);
        }
        __builtin_amdgcn_s_barrier();
    }

    // ---- epilogue: C/D layout col = lane&15, row = (lane>>4)*4 + reg ----
    const int rb = kq * 4;
    #pragma unroll
    for (int mi = 0; mi < 8; ++mi) {
        #pragma unroll
        for (int n = 0; n < 4; ++n) {
            const int col = tn + wn * 64 + n * 16 + fr;
            const float bcol = (EPI == 1) ? bias[col] : 0.f;
            #pragma unroll
            for (int j = 0; j < 4; ++j) {
                const int row = tm + wm * 128 + mi * 16 + rb + j;
                float v = acc[mi][n][j];
                if (EPI == 1) v += rs[row] * bcol;
                else          v *= rs[row];
                C[(size_t)row * N + col] = (short)f2bf(v);
            }
        }
    }
}

// ---------------- CSR aggregation:  Y[i] = inv_in[i] * sum_{e: dst=i} X[src[e]] ----------------
template<int RELU>
__global__ __launch_bounds__(256)
void agg_csr(const short* __restrict__ X, short* __restrict__ Y,
             const int* __restrict__ row_off, const int* __restrict__ esrc,
             const float* __restrict__ inv_in, int F)
{
    const int node = blockIdx.y;
    const int c0 = (blockIdx.x * blockDim.x + threadIdx.x) * 8;
    float acc[8];
    #pragma unroll
    for (int j = 0; j < 8; ++j) acc[j] = 0.f;

    const int beg = row_off[node], end = row_off[node + 1];
    int p = beg;
    for (; p + 3 < end; p += 4) {
        const int s0 = esrc[p], s1 = esrc[p + 1], s2 = esrc[p + 2], s3 = esrc[p + 3];
        bf8 x0 = *reinterpret_cast<const bf8*>(X + (size_t)s0 * F + c0);
        bf8 x1 = *reinterpret_cast<const bf8*>(X + (size_t)s1 * F + c0);
        bf8 x2 = *reinterpret_cast<const bf8*>(X + (size_t)s2 * F + c0);
        bf8 x3 = *reinterpret_cast<const bf8*>(X + (size_t)s3 * F + c0);
        #pragma unroll
        for (int j = 0; j < 8; ++j)
            acc[j] += (bf2f((unsigned short)x0[j]) + bf2f((unsigned short)x1[j]))
                    + (bf2f((unsigned short)x2[j]) + bf2f((unsigned short)x3[j]));
    }
    for (; p < end; ++p) {
        const int s0 = esrc[p];
        bf8 x0 = *reinterpret_cast<const bf8*>(X + (size_t)s0 * F + c0);
        #pragma unroll
        for (int j = 0; j < 8; ++j) acc[j] += bf2f((unsigned short)x0[j]);
    }
    const float sc = inv_in[node];
    bf8 o;
    #pragma unroll
    for (int j = 0; j < 8; ++j) {
        float v = acc[j] * sc;
        if (RELU) v = fmaxf(v, 0.f);
        o[j] = (short)f2bf(v);
    }
    *reinterpret_cast<bf8*>(Y + (size_t)node * F + c0) = o;
}

// ---------------- head: logits = H[4096] . Wl[4096][16] + bl; softmax ----------------
__global__ __launch_bounds__(256)
void k_head(const short* __restrict__ H, const float* __restrict__ Wl,
            const float* __restrict__ bl, float* __restrict__ out)
{
    const int row = blockIdx.x;
    const int tid = threadIdx.x;
    float acc[16];
    #pragma unroll
    for (int c = 0; c < 16; ++c) acc[c] = 0.f;

    for (int k = tid; k < 4096; k += 256) {
        const float x = bf2f((unsigned short)H[(size_t)row * 4096 + k]);
        const float4* w = reinterpret_cast<const float4*>(Wl + (size_t)k * 16);
        float4 w0 = w[0], w1 = w[1], w2 = w[2], w3 = w[3];
        acc[0]  += x * w0.x; acc[1]  += x * w0.y; acc[2]  += x * w0.z; acc[3]  += x * w0.w;
        acc[4]  += x * w1.x; acc[5]  += x * w1.y; acc[6]  += x * w1.z; acc[7]  += x * w1.w;
        acc[8]  += x * w2.x; acc[9]  += x * w2.y; acc[10] += x * w2.z; acc[11] += x * w2.w;
        acc[12] += x * w3.x; acc[13] += x * w3.y; acc[14] += x * w3.z; acc[15] += x * w3.w;
    }
    #pragma unroll
    for (int c = 0; c < 16; ++c)
        for (int off = 32; off; off >>= 1)
            acc[c] += __shfl_down(acc[c], off, 64);

    __shared__ float sm[16][4];
    const int wid = tid >> 6, lane = tid & 63;
    if (lane == 0) {
        #pragma unroll
        for (int c = 0; c < 16; ++c) sm[c][wid] = acc[c];
    }
    __syncthreads();
    if (tid < 16) {
        float l = sm[tid][0] + sm[tid][1] + sm[tid][2] + sm[tid][3] + bl[tid];
        float mx = l;
        #pragma unroll
        for (int off = 1; off < 16; off <<= 1) mx = fmaxf(mx, __shfl_xor(mx, off, 16));
        float e = expf(l - mx);
        float s = e;
        #pragma unroll
        for (int off = 1; off < 16; off <<= 1) s += __shfl_xor(s, off, 16);
        out[(size_t)row * 16 + tid] = e / s;
    }
}

// ---------------- launch ----------------

extern "C" void kernel_launch(void* const* d_in, const int* in_sizes, int n_in,
                              void* d_out, int out_size, void* d_ws, size_t ws_size,
                              hipStream_t stream)
{
    const float* features = (const float*)d_in[0];
    const float* W1       = (const float*)d_in[1];
    const float* b1       = (const float*)d_in[2];
    const float* W2       = (const float*)d_in[3];
    const float* Wl       = (const float*)d_in[4];
    const float* bl       = (const float*)d_in[5];
    const int*   src      = (const int*)d_in[6];
    const int*   dst      = (const int*)d_in[7];
    float* out = (float*)d_out;

    const int N = 4096, IN = 512, H = 8192;
    const int E = in_sizes[6];

    char* ws = (char*)d_ws;
    size_t o = 0;
    auto alloc = [&](size_t bytes) -> char* {
        char* p = ws + o;
        o = (o + bytes + 255) & ~(size_t)255;
        return p;
    };
    short* W2t   = (short*)alloc((size_t)N * H * 2);     // 64 MB  W2^T bf16 [4096][8192]
    short* h1    = (short*)alloc((size_t)N * H * 2);     // 64 MB  conv1 out bf16 [4096][8192]
    short* x2s   = (short*)alloc((size_t)N * N * 2);     // 32 MB  (h1 W2)*inv_out bf16
    short* featb = (short*)alloc((size_t)N * IN * 2);    // 4 MB   features*inv_out bf16
    short* aggF  = (short*)alloc((size_t)N * IN * 2);    // 4 MB   A_hat X bf16
    short* W1t   = (short*)alloc((size_t)H * IN * 2);    // 8 MB   W1^T bf16 [8192][512]
    float* deg_out = (float*)alloc(N * 4);
    float* deg_in  = (float*)alloc(N * 4);
    float* inv_out = (float*)alloc(N * 4);
    float* inv_in  = (float*)alloc(N * 4);
    float* rowsum  = (float*)alloc(N * 4);
    int*   cursor  = (int*)alloc(N * 4);
    int*   row_off = (int*)alloc((N + 1) * 4);
    int*   esrc    = (int*)alloc((size_t)E * 4);
    short* h2 = h1;   // alias: h1 dead after GEMM2, h2 written by agg2

    // graph prep
    k_zero <<<(N + 255) / 256, 256, 0, stream>>>(deg_out, deg_in, cursor, N);
    k_count<<<(E + 255) / 256, 256, 0, stream>>>(src, dst, deg_out, deg_in, E);
    k_inv  <<<(N + 255) / 256, 256, 0, stream>>>(deg_out, deg_in, inv_out, inv_in, N);
    k_scan <<<1, 1024, 0, stream>>>(deg_in, row_off);
    k_fill <<<(E + 255) / 256, 256, 0, stream>>>(src, dst, row_off, cursor, esrc, E);
    k_rowsum<<<N, 64, 0, stream>>>(row_off, esrc, inv_out, inv_in, rowsum);

    // operand conversion
    k_cvt_scale<<<(N * IN / 4 + 255) / 256, 256, 0, stream>>>(features, inv_out, featb,
                                                              N * IN / 4, IN / 4);
    k_tr2<<<dim3(H / 32, IN / 64), dim3(32, 8), 0, stream>>>(W1, W1t, IN, H);
    k_tr2<<<dim3(N / 32, H / 64), dim3(32, 8), 0, stream>>>(W2, W2t, H, N);

    // conv1: aggregate features first (F=512), then GEMM1 with rowsum*b1 epilogue
    agg_csr<0><<<dim3(1, N), 64, 0, stream>>>(featb, aggF, row_off, esrc, inv_in, IN);
    gemm8p<1><<<dim3(H / 256, N / 256), 512, 0, stream>>>(aggF, W1t, h1, b1, rowsum, N, H, IN);

    // conv2: project first, then aggregate
    gemm8p<2><<<dim3(N / 256, N / 256), 512, 0, stream>>>(h1, W2t, x2s, nullptr, inv_out, N, N, H);
    agg_csr<1><<<dim3(N / 2048, N), 256, 0, stream>>>(x2s, h2, row_off, esrc, inv_in, N);

    // head + softmax
    k_head<<<N, 256, 0, stream>>>(h2, Wl, bl, out);
}

// Round 6
// 476.033 us; speedup vs baseline: 2.0906x; 1.1552x over previous
//
#include <hip/hip_runtime.h>
#include <cstdint>
#include <cstddef>

// ---------------------------------------------------------------------------
// GCN forward:  softmax( (A_hat relu(A_hat (X W1 + b1) W2)) Wl + bl )
// conv1 reordered: aggregate features (F=512) first, GEMM1 epilogue adds
// rowsum*b1. conv2: project (8192->4096) then aggregate.
// GEMM (R6): 256x256 tile, BK=64, 8 waves (2M x 4N), 2-buffer LDS (128KB)
// with SAME-BUFFER region ring: stage tile t+2's B after P1 (B dead),
// A after P2 (A dead); counted vmcnt(8) at end of tile (t+1 landed, t+2's
// 8 loads stay in flight - never drain to 0 in steady state). 4 phases of
// 16 MFMA each; B/A fragments register-cached across phases.
// T2 XOR swizzle (both sides), T5 setprio, bijective XCD-chunk swizzle.
// agg2 (R6): 512-col stripes pinned to XCDs via bid%8 -> gather from L2.
// ---------------------------------------------------------------------------

using bf8   = __attribute__((ext_vector_type(8))) short;   // 8 bf16 (4 VGPR)
using s4    = __attribute__((ext_vector_type(4))) short;
using f32x4 = __attribute__((ext_vector_type(4))) float;

static __device__ __forceinline__ unsigned short f2bf(float f) {
    union { float f; uint32_t u; } v; v.f = f;
    uint32_t r = (v.u + 0x7FFFu + ((v.u >> 16) & 1u)) >> 16;   // RNE
    return (unsigned short)r;
}
static __device__ __forceinline__ float bf2f(unsigned short b) {
    union { uint32_t u; float f; } v; v.u = ((uint32_t)b) << 16;
    return v.f;
}

static __device__ __forceinline__ void gload16(const short* g, short* l) {
    __builtin_amdgcn_global_load_lds(
        (const __attribute__((address_space(1))) unsigned int*)g,
        (__attribute__((address_space(3))) unsigned int*)l,
        16, 0, 0);
}

// ---------------- prep kernels ----------------

__global__ void k_zero(float* a, float* b, int* c, int n) {
    int i = blockIdx.x * blockDim.x + threadIdx.x;
    if (i < n) { a[i] = 0.f; b[i] = 0.f; c[i] = 0; }
}

__global__ void k_count(const int* __restrict__ src, const int* __restrict__ dst,
                        float* deg_out, float* deg_in, int E) {
    int e = blockIdx.x * blockDim.x + threadIdx.x;
    if (e < E) {
        atomicAdd(&deg_out[src[e]], 1.f);
        atomicAdd(&deg_in[dst[e]], 1.f);
    }
}

__global__ void k_inv(const float* deg_out, const float* deg_in,
                      float* inv_out, float* inv_in, int n) {
    int i = blockIdx.x * blockDim.x + threadIdx.x;
    if (i < n) {
        inv_out[i] = rsqrtf(fmaxf(deg_out[i], 1.f));
        inv_in[i]  = rsqrtf(fmaxf(deg_in[i], 1.f));
    }
}

__global__ void k_scan(const float* __restrict__ deg_in, int* __restrict__ row_off) {
    __shared__ int part[1024];
    const int t = threadIdx.x;
    int v0 = (int)deg_in[t*4+0], v1 = (int)deg_in[t*4+1],
        v2 = (int)deg_in[t*4+2], v3 = (int)deg_in[t*4+3];
    part[t] = v0 + v1 + v2 + v3;
    __syncthreads();
    for (int off = 1; off < 1024; off <<= 1) {
        int x = (t >= off) ? part[t - off] : 0;
        __syncthreads();
        part[t] += x;
        __syncthreads();
    }
    int run = (t == 0) ? 0 : part[t-1];
    row_off[t*4+0] = run; run += v0;
    row_off[t*4+1] = run; run += v1;
    row_off[t*4+2] = run; run += v2;
    row_off[t*4+3] = run; run += v3;
    if (t == 1023) row_off[4096] = run;
}

__global__ void k_fill(const int* __restrict__ src, const int* __restrict__ dst,
                       const int* __restrict__ row_off, int* cursor,
                       int* __restrict__ esrc, int E) {
    int e = blockIdx.x * blockDim.x + threadIdx.x;
    if (e < E) {
        int d = dst[e];
        int p = atomicAdd(&cursor[d], 1);
        esrc[row_off[d] + p] = src[e];
    }
}

__global__ void k_rowsum(const int* __restrict__ row_off, const int* __restrict__ esrc,
                         const float* __restrict__ inv_out, const float* __restrict__ inv_in,
                         float* __restrict__ rowsum) {
    const int node = blockIdx.x, lane = threadIdx.x;
    const int beg = row_off[node], end = row_off[node + 1];
    float s = 0.f;
    for (int p = beg + lane; p < end; p += 64) s += inv_out[esrc[p]];
    #pragma unroll
    for (int off = 32; off; off >>= 1) s += __shfl_down(s, off, 64);
    if (lane == 0) rowsum[node] = s * inv_in[node];
}

__global__ void k_cvt_scale(const float* __restrict__ in, const float* __restrict__ sc,
                            short* __restrict__ out, int n4, int f4) {
    int i = blockIdx.x * blockDim.x + threadIdx.x;
    if (i < n4) {
        const float s = sc[i / f4];
        float4 v = reinterpret_cast<const float4*>(in)[i];
        s4 o;
        o[0] = (short)f2bf(v.x * s); o[1] = (short)f2bf(v.y * s);
        o[2] = (short)f2bf(v.z * s); o[3] = (short)f2bf(v.w * s);
        reinterpret_cast<s4*>(out)[i] = o;
    }
}

// fp32 [R][C] -> bf16 [C][R]; 64(r)x32(c) tile, block (32,8), ushort2 writes
__global__ void k_tr2(const float* __restrict__ in, short* __restrict__ out, int R, int C) {
    __shared__ float tile[64][33];
    const int bc = blockIdx.x * 32, br = blockIdx.y * 64;
    const int tx = threadIdx.x, ty = threadIdx.y;
    #pragma unroll
    for (int dy = 0; dy < 64; dy += 8)
        tile[ty + dy][tx] = in[(size_t)(br + ty + dy) * C + bc + tx];
    __syncthreads();
    #pragma unroll
    for (int dy = 0; dy < 32; dy += 8) {
        const int oy = ty + dy;
        ushort2 o;
        o.x = f2bf(tile[tx * 2][oy]);
        o.y = f2bf(tile[tx * 2 + 1][oy]);
        *reinterpret_cast<ushort2*>(&out[(size_t)(bc + oy) * R + br + tx * 2]) = o;
    }
}

// ---------------- bf16 MFMA GEMM, 4-phase counted-vmcnt pipeline ----------------
// C[M][N] = A[M][K] * Bt^T; A row-major, Bt = B^T row-major [N][K], all bf16.
// EPI==1: out = acc + rs[row]*bias[col]; EPI==2: out = acc * rs[row].
// Tile 256x256, BK=64. 8 waves = 2M x 4N, wave tile 128x64.
// LDS: 2 buffers x (A[256][64] + B[256][64]) = 128KB; tile t in buf[t&1].
// Stage of tile t+2 goes into buf[t&1] (the buffer being computed!) using
// region-death ordering: B region dead after P1's reads (frags reg-cached),
// A region dead after P2's reads. Stage B(t+2) in P2's slot, A(t+2) in P3's
// slot; each slot is after the preceding phase's 2nd barrier, and a wave
// reaches that barrier only after its lgkm0 => all reads of the dead region
// completed workgroup-wide before the overwriting loads are issued.
// vmcnt(8) at end of tile leaves exactly t+2's 8 loads in flight => t+1
// fully landed before its P0 (barrier joins all waves' waits). Drain to 0
// only at t==nt-2. Per-phase: 16 MFMA. Reads/phase: 12/4/8/0.
// Requires nt >= 2 and M%256==N%256==K%64==0; grid nwg%8==0 (XCD swizzle).
template<int EPI>
__global__ __launch_bounds__(512, 2)
void gemm8p(const short* __restrict__ A, const short* __restrict__ Bt,
            short* __restrict__ C,
            const float* __restrict__ bias, const float* __restrict__ rs,
            int M, int N, int K)
{
    constexpr int USZ  = 4096;            // shorts per 64-row x 64-short unit
    constexpr int BOFF = 4 * USZ;         // B region offset within buffer (16384)
    constexpr int BUF  = 8 * USZ;         // shorts per buffer (32768 = 64KB)
    __shared__ __align__(16) short lds[2 * BUF];   // 128 KB
    const int tid  = threadIdx.x;
    const int wid  = tid >> 6, lane = tid & 63;
    const int wm   = wid >> 2;            // 0..1  (M wave index)
    const int wn   = wid & 3;             // 0..3  (N wave index)
    const int fr   = lane & 15;
    const int kq   = lane >> 4;           // 0..3
    const int nt   = K >> 6;

    // bijective XCD-chunk swizzle (nwg % 8 == 0)
    const int gx  = gridDim.x;
    const int nwg = gx * gridDim.y;
    int bid = blockIdx.y * gx + blockIdx.x;
    bid = (bid & 7) * (nwg >> 3) + (bid >> 3);
    const int tm = (bid / gx) * 256;
    const int tn = (bid % gx) * 256;

    // ---- staging addressing (per thread: 1 gload16 per 8KB unit) ----
    const int srow = tid >> 3;            // 0..63 row within unit
    const int scq  = tid & 7;             // linear 16B-chunk within row
    const int scs  = scq ^ (srow & 7);    // pre-swizzled source chunk
    const short* gA = A  + (size_t)(tm + srow) * K + scs * 8;
    const short* gB = Bt + (size_t)(tn + srow) * K + scs * 8;
    short* const ldst = lds + tid * 8;    // + bufoff + unit*USZ (shorts)

    // ---- fragment read offsets (shorts, lane-constant) ----
    const int cx0 = (0 * 4 + kq) ^ (fr & 7);
    const int cx1 = (1 * 4 + kq) ^ (fr & 7);
    int aoff[8][2], boff[4][2];
    #pragma unroll
    for (int mi = 0; mi < 8; ++mi) {
        const int r = wm * 128 + mi * 16 + fr;
        aoff[mi][0] = r * 64 + cx0 * 8;
        aoff[mi][1] = r * 64 + cx1 * 8;
    }
    #pragma unroll
    for (int n = 0; n < 4; ++n) {
        const int r = wn * 64 + n * 16 + fr;
        boff[n][0] = BOFF + r * 64 + cx0 * 8;
        boff[n][1] = BOFF + r * 64 + cx1 * 8;
    }

    f32x4 acc[8][4];
    #pragma unroll
    for (int mi = 0; mi < 8; ++mi)
        #pragma unroll
        for (int n = 0; n < 4; ++n)
            acc[mi][n] = (f32x4){0.f, 0.f, 0.f, 0.f};

    // ---- prologue: stage tile 0 -> buf0, tile 1 -> buf1; wait tile 0 ----
    #pragma unroll
    for (int u = 0; u < 4; ++u) gload16(gA + (size_t)u * 64 * K, ldst + u * USZ);
    #pragma unroll
    for (int v = 0; v < 4; ++v) gload16(gB + (size_t)v * 64 * K, ldst + BOFF + v * USZ);
    #pragma unroll
    for (int u = 0; u < 4; ++u) gload16(gA + (size_t)u * 64 * K + 64, ldst + BUF + u * USZ);
    #pragma unroll
    for (int v = 0; v < 4; ++v) gload16(gB + (size_t)v * 64 * K + 64, ldst + BUF + BOFF + v * USZ);
    asm volatile("s_waitcnt vmcnt(8)" ::: "memory");   // tile 0 landed
    __builtin_amdgcn_sched_barrier(0);
    __builtin_amdgcn_s_barrier();

    for (int t = 0; t < nt; ++t) {
        const int cc = (t & 1) * BUF;          // compute buffer == stage target for t+2
        const bool pf = (t + 2 < nt);
        const size_t kf = (size_t)(t + 2) * 64;

        bf8 a03[4][2], a47[4][2], bg[4][2];

        // ---- P0: read A m0-3 (8) + B n0-1 (4); 16 MFMA (m0-3 x n0-1) ----
        #pragma unroll
        for (int mi = 0; mi < 4; ++mi)
            #pragma unroll
            for (int s = 0; s < 2; ++s)
                a03[mi][s] = *reinterpret_cast<const bf8*>(lds + cc + aoff[mi][s]);
        #pragma unroll
        for (int n = 0; n < 2; ++n)
            #pragma unroll
            for (int s = 0; s < 2; ++s)
                bg[n][s] = *reinterpret_cast<const bf8*>(lds + cc + boff[n][s]);
        __builtin_amdgcn_s_barrier();
        asm volatile("s_waitcnt lgkmcnt(0)" ::: "memory");
        __builtin_amdgcn_sched_barrier(0);
        __builtin_amdgcn_s_setprio(1);
        #pragma unroll
        for (int mi = 0; mi < 4; ++mi)
            #pragma unroll
            for (int n = 0; n < 2; ++n)
                #pragma unroll
                for (int s = 0; s < 2; ++s)
                    acc[mi][n] = __builtin_amdgcn_mfma_f32_16x16x32_bf16(a03[mi][s], bg[n][s], acc[mi][n], 0, 0, 0);
        __builtin_amdgcn_s_setprio(0);
        __builtin_amdgcn_s_barrier();

        // ---- P1: read B n2-3 (4); 16 MFMA (m0-3 x n2-3) ----
        #pragma unroll
        for (int n = 2; n < 4; ++n)
            #pragma unroll
            for (int s = 0; s < 2; ++s)
                bg[n][s] = *reinterpret_cast<const bf8*>(lds + cc + boff[n][s]);
        __builtin_amdgcn_s_barrier();
        asm volatile("s_waitcnt lgkmcnt(0)" ::: "memory");
        __builtin_amdgcn_sched_barrier(0);
        __builtin_amdgcn_s_setprio(1);
        #pragma unroll
        for (int mi = 0; mi < 4; ++mi)
            #pragma unroll
            for (int n = 2; n < 4; ++n)
                #pragma unroll
                for (int s = 0; s < 2; ++s)
                    acc[mi][n] = __builtin_amdgcn_mfma_f32_16x16x32_bf16(a03[mi][s], bg[n][s], acc[mi][n], 0, 0, 0);
        __builtin_amdgcn_s_setprio(0);
        __builtin_amdgcn_s_barrier();
        // B region of tile t now dead (frags reg-cached) and all waves past
        // their lgkm0 => safe to overwrite below.

        // ---- P2: read A m4-7 (8); stage B(t+2) into cc; 16 MFMA (m4-7 x n0-1) ----
        #pragma unroll
        for (int mi = 0; mi < 4; ++mi)
            #pragma unroll
            for (int s = 0; s < 2; ++s)
                a47[mi][s] = *reinterpret_cast<const bf8*>(lds + cc + aoff[4 + mi][s]);
        if (pf) {
            #pragma unroll
            for (int v = 0; v < 4; ++v)
                gload16(gB + (size_t)v * 64 * K + kf, ldst + cc + BOFF + v * USZ);
        }
        __builtin_amdgcn_s_barrier();
        asm volatile("s_waitcnt lgkmcnt(0)" ::: "memory");
        __builtin_amdgcn_sched_barrier(0);
        __builtin_amdgcn_s_setprio(1);
        #pragma unroll
        for (int mi = 0; mi < 4; ++mi)
            #pragma unroll
            for (int n = 0; n < 2; ++n)
                #pragma unroll
                for (int s = 0; s < 2; ++s)
                    acc[4 + mi][n] = __builtin_amdgcn_mfma_f32_16x16x32_bf16(a47[mi][s], bg[n][s], acc[4 + mi][n], 0, 0, 0);
        __builtin_amdgcn_s_setprio(0);
        __builtin_amdgcn_s_barrier();
        // A region of tile t now dead => safe to overwrite below.

        // ---- P3: stage A(t+2) into cc; 16 MFMA (m4-7 x n2-3); counted wait ----
        if (pf) {
            #pragma unroll
            for (int u = 0; u < 4; ++u)
                gload16(gA + (size_t)u * 64 * K + kf, ldst + cc + u * USZ);
        }
        __builtin_amdgcn_s_setprio(1);
        #pragma unroll
        for (int mi = 0; mi < 4; ++mi)
            #pragma unroll
            for (int n = 2; n < 4; ++n)
                #pragma unroll
                for (int s = 0; s < 2; ++s)
                    acc[4 + mi][n] = __builtin_amdgcn_mfma_f32_16x16x32_bf16(a47[mi][s], bg[n][s], acc[4 + mi][n], 0, 0, 0);
        __builtin_amdgcn_s_setprio(0);
        if (pf) {
            asm volatile("s_waitcnt vmcnt(8)" ::: "memory");   // t+1 landed; t+2 in flight
        } else if (t + 2 == nt) {
            asm volatile("s_waitcnt vmcnt(0)" ::: "memory");   // last prefetched tile
        }
        __builtin_amdgcn_sched_barrier(0);
        __builtin_amdgcn_s_barrier();
    }

    // ---- epilogue: C/D layout col = lane&15, row = (lane>>4)*4 + reg ----
    const int rb = kq * 4;
    #pragma unroll
    for (int mi = 0; mi < 8; ++mi) {
        #pragma unroll
        for (int n = 0; n < 4; ++n) {
            const int col = tn + wn * 64 + n * 16 + fr;
            const float bcol = (EPI == 1) ? bias[col] : 0.f;
            #pragma unroll
            for (int j = 0; j < 4; ++j) {
                const int row = tm + wm * 128 + mi * 16 + rb + j;
                float v = acc[mi][n][j];
                if (EPI == 1) v += rs[row] * bcol;
                else          v *= rs[row];
                C[(size_t)row * N + col] = (short)f2bf(v);
            }
        }
    }
}

// ---------------- CSR aggregation, L2-striped ----------------
// Y[i] = inv_in[i] * sum_{e: dst=i} X[src[e]].  Column stripe of 512 cols
// (= 4 MB of X at F=4096) is pinned to one XCD: linear bid % 8 ==
// blockIdx.x == stripe, and dispatch round-robins linear bid across XCDs,
// so all gathers of a stripe hit that XCD's L2. 64-thread blocks.
template<int RELU>
__global__ __launch_bounds__(64)
void agg_strip(const short* __restrict__ X, short* __restrict__ Y,
               const int* __restrict__ row_off, const int* __restrict__ esrc,
               const float* __restrict__ inv_in, int F)
{
    const int node = blockIdx.y;
    const int c0 = blockIdx.x * 512 + threadIdx.x * 8;
    float acc[8];
    #pragma unroll
    for (int j = 0; j < 8; ++j) acc[j] = 0.f;

    const int beg = row_off[node], end = row_off[node + 1];
    int p = beg;
    for (; p + 3 < end; p += 4) {
        const int s0 = esrc[p], s1 = esrc[p + 1], s2 = esrc[p + 2], s3 = esrc[p + 3];
        bf8 x0 = *reinterpret_cast<const bf8*>(X + (size_t)s0 * F + c0);
        bf8 x1 = *reinterpret_cast<const bf8*>(X + (size_t)s1 * F + c0);
        bf8 x2 = *reinterpret_cast<const bf8*>(X + (size_t)s2 * F + c0);
        bf8 x3 = *reinterpret_cast<const bf8*>(X + (size_t)s3 * F + c0);
        #pragma unroll
        for (int j = 0; j < 8; ++j)
            acc[j] += (bf2f((unsigned short)x0[j]) + bf2f((unsigned short)x1[j]))
                    + (bf2f((unsigned short)x2[j]) + bf2f((unsigned short)x3[j]));
    }
    for (; p < end; ++p) {
        const int s0 = esrc[p];
        bf8 x0 = *reinterpret_cast<const bf8*>(X + (size_t)s0 * F + c0);
        #pragma unroll
        for (int j = 0; j < 8; ++j) acc[j] += bf2f((unsigned short)x0[j]);
    }
    const float sc = inv_in[node];
    bf8 o;
    #pragma unroll
    for (int j = 0; j < 8; ++j) {
        float v = acc[j] * sc;
        if (RELU) v = fmaxf(v, 0.f);
        o[j] = (short)f2bf(v);
    }
    *reinterpret_cast<bf8*>(Y + (size_t)node * F + c0) = o;
}

// ---------------- head: logits = H[4096] . Wl[4096][16] + bl; softmax ----------------
__global__ __launch_bounds__(256)
void k_head(const short* __restrict__ H, const float* __restrict__ Wl,
            const float* __restrict__ bl, float* __restrict__ out)
{
    const int row = blockIdx.x;
    const int tid = threadIdx.x;
    float acc[16];
    #pragma unroll
    for (int c = 0; c < 16; ++c) acc[c] = 0.f;

    for (int k = tid; k < 4096; k += 256) {
        const float x = bf2f((unsigned short)H[(size_t)row * 4096 + k]);
        const float4* w = reinterpret_cast<const float4*>(Wl + (size_t)k * 16);
        float4 w0 = w[0], w1 = w[1], w2 = w[2], w3 = w[3];
        acc[0]  += x * w0.x; acc[1]  += x * w0.y; acc[2]  += x * w0.z; acc[3]  += x * w0.w;
        acc[4]  += x * w1.x; acc[5]  += x * w1.y; acc[6]  += x * w1.z; acc[7]  += x * w1.w;
        acc[8]  += x * w2.x; acc[9]  += x * w2.y; acc[10] += x * w2.z; acc[11] += x * w2.w;
        acc[12] += x * w3.x; acc[13] += x * w3.y; acc[14] += x * w3.z; acc[15] += x * w3.w;
    }
    #pragma unroll
    for (int c = 0; c < 16; ++c)
        for (int off = 32; off; off >>= 1)
            acc[c] += __shfl_down(acc[c], off, 64);

    __shared__ float sm[16][4];
    const int wid = tid >> 6, lane = tid & 63;
    if (lane == 0) {
        #pragma unroll
        for (int c = 0; c < 16; ++c) sm[c][wid] = acc[c];
    }
    __syncthreads();
    if (tid < 16) {
        float l = sm[tid][0] + sm[tid][1] + sm[tid][2] + sm[tid][3] + bl[tid];
        float mx = l;
        #pragma unroll
        for (int off = 1; off < 16; off <<= 1) mx = fmaxf(mx, __shfl_xor(mx, off, 16));
        float e = expf(l - mx);
        float s = e;
        #pragma unroll
        for (int off = 1; off < 16; off <<= 1) s += __shfl_xor(s, off, 16);
        out[(size_t)row * 16 + tid] = e / s;
    }
}

// ---------------- launch ----------------

extern "C" void kernel_launch(void* const* d_in, const int* in_sizes, int n_in,
                              void* d_out, int out_size, void* d_ws, size_t ws_size,
                              hipStream_t stream)
{
    const float* features = (const float*)d_in[0];
    const float* W1       = (const float*)d_in[1];
    const float* b1       = (const float*)d_in[2];
    const float* W2       = (const float*)d_in[3];
    const float* Wl       = (const float*)d_in[4];
    const float* bl       = (const float*)d_in[5];
    const int*   src      = (const int*)d_in[6];
    const int*   dst      = (const int*)d_in[7];
    float* out = (float*)d_out;

    const int N = 4096, IN = 512, H = 8192;
    const int E = in_sizes[6];

    char* ws = (char*)d_ws;
    size_t o = 0;
    auto alloc = [&](size_t bytes) -> char* {
        char* p = ws + o;
        o = (o + bytes + 255) & ~(size_t)255;
        return p;
    };
    short* W2t   = (short*)alloc((size_t)N * H * 2);     // 64 MB  W2^T bf16 [4096][8192]
    short* h1    = (short*)alloc((size_t)N * H * 2);     // 64 MB  conv1 out bf16 [4096][8192]
    short* x2s   = (short*)alloc((size_t)N * N * 2);     // 32 MB  (h1 W2)*inv_out bf16
    short* featb = (short*)alloc((size_t)N * IN * 2);    // 4 MB   features*inv_out bf16
    short* aggF  = (short*)alloc((size_t)N * IN * 2);    // 4 MB   A_hat X bf16
    short* W1t   = (short*)alloc((size_t)H * IN * 2);    // 8 MB   W1^T bf16 [8192][512]
    float* deg_out = (float*)alloc(N * 4);
    float* deg_in  = (float*)alloc(N * 4);
    float* inv_out = (float*)alloc(N * 4);
    float* inv_in  = (float*)alloc(N * 4);
    float* rowsum  = (float*)alloc(N * 4);
    int*   cursor  = (int*)alloc(N * 4);
    int*   row_off = (int*)alloc((N + 1) * 4);
    int*   esrc    = (int*)alloc((size_t)E * 4);
    short* h2 = h1;   // alias: h1 dead after GEMM2, h2 written by agg2

    // graph prep
    k_zero <<<(N + 255) / 256, 256, 0, stream>>>(deg_out, deg_in, cursor, N);
    k_count<<<(E + 255) / 256, 256, 0, stream>>>(src, dst, deg_out, deg_in, E);
    k_inv  <<<(N + 255) / 256, 256, 0, stream>>>(deg_out, deg_in, inv_out, inv_in, N);
    k_scan <<<1, 1024, 0, stream>>>(deg_in, row_off);
    k_fill <<<(E + 255) / 256, 256, 0, stream>>>(src, dst, row_off, cursor, esrc, E);
    k_rowsum<<<N, 64, 0, stream>>>(row_off, esrc, inv_out, inv_in, rowsum);

    // operand conversion
    k_cvt_scale<<<(N * IN / 4 + 255) / 256, 256, 0, stream>>>(features, inv_out, featb,
                                                              N * IN / 4, IN / 4);
    k_tr2<<<dim3(H / 32, IN / 64), dim3(32, 8), 0, stream>>>(W1, W1t, IN, H);
    k_tr2<<<dim3(N / 32, H / 64), dim3(32, 8), 0, stream>>>(W2, W2t, H, N);

    // conv1: aggregate features first (F=512), then GEMM1 with rowsum*b1 epilogue
    agg_strip<0><<<dim3(1, N), 64, 0, stream>>>(featb, aggF, row_off, esrc, inv_in, IN);
    gemm8p<1><<<dim3(H / 256, N / 256), 512, 0, stream>>>(aggF, W1t, h1, b1, rowsum, N, H, IN);

    // conv2: project first, then aggregate (L2-striped: stripe = bid%8 = XCD)
    gemm8p<2><<<dim3(N / 256, N / 256), 512, 0, stream>>>(h1, W2t, x2s, nullptr, inv_out, N, N, H);
    agg_strip<1><<<dim3(N / 512, N), 64, 0, stream>>>(x2s, h2, row_off, esrc, inv_in, N);

    // head + softmax
    k_head<<<N, 256, 0, stream>>>(h2, Wl, bl, out);
}